// Round 2
// baseline (261.865 us; speedup 1.0000x reference)
//
#include <hip/hip_runtime.h>

typedef __bf16 bf16x8 __attribute__((ext_vector_type(8)));
typedef float f32x4 __attribute__((ext_vector_type(4)));
typedef float fv4 __attribute__((ext_vector_type(4)));

#define B_ 8
#define T_ 2048
#define C_ 1024
#define H_ 128

// async global->LDS, 16B per lane. LDS dest = wave-uniform base + lane*16.
__device__ __forceinline__ void gload16(void* lds, const void* g) {
  __builtin_amdgcn_global_load_lds(
      (const __attribute__((address_space(1))) void*)g,
      (__attribute__((address_space(3))) void*)lds, 16, 0, 0);
}

// ---------------- prep: W[1024][128] fp32 -> Wt[wsel][128][1024] bf16 ----------------
// Also zeroes the split-K arrival counters (stream order: prep -> proj -> attn_split).
__global__ __launch_bounds__(256) void prep_kernel(
    const float* __restrict__ Wq, const float* __restrict__ Wk,
    const float* __restrict__ Wv, __bf16* __restrict__ Wt, int* __restrict__ Cnt)
{
  __shared__ __bf16 ldsT[128 * 136];
  const int tid = threadIdx.x;
  const int k0 = blockIdx.x * 128;
  const int wsel = blockIdx.y;
  if (Cnt && blockIdx.x == 0 && blockIdx.y == 0) Cnt[tid] = 0;  // 256 counters
  const float* W = wsel == 0 ? Wq : (wsel == 1 ? Wk : Wv);
#pragma unroll
  for (int i = 0; i < 16; ++i) {
    int fidx = tid + 256 * i;
    int k = fidx >> 5, h4 = (fidx & 31) << 2;
    fv4 w = *(const fv4*)(W + (size_t)(k0 + k) * H_ + h4);
#pragma unroll
    for (int j = 0; j < 4; ++j) ldsT[(h4 + j) * 136 + k] = (__bf16)w[j];
  }
  __syncthreads();
#pragma unroll
  for (int i = 0; i < 8; ++i) {
    int sidx = tid + 256 * i;
    int h = sidx >> 4, c8 = (sidx & 15) << 3;
    *(bf16x8*)(Wt + (size_t)wsel * H_ * C_ + (size_t)h * C_ + k0 + c8) =
        *(const bf16x8*)&ldsT[h * 136 + c8];
  }
}

// ---------------- fused QKV projection, v2: 2-phase global_load_lds pipeline ----------
// GEMM M=16384 N=384 K=1024. Block = 64 rows x 192 cols, grid (256,2) -> 2 blocks/CU.
// 4 waves (2x2), wave tile 32x96 = acc[2][6], BK=64 -> 24 MFMA/wave per barrier,
// ONE __syncthreads per K-step. Staging is pure DMA; XOR-swizzled global SOURCE +
// swizzled ds_read (rule 21) keeps fragment reads bank-conflict-free.
__global__ __launch_bounds__(256) void proj_kernel(
    const float* __restrict__ x, const __bf16* __restrict__ Wt,
    __bf16* __restrict__ Qw, __bf16* __restrict__ Kw, __bf16* __restrict__ Vtw)
{
  __shared__ __align__(16) float ldsA[2][64 * 64];     // 2 x 16 KB
  __shared__ __align__(16) __bf16 ldsB[2][192 * 64];   // 2 x 24 KB  (total 80 KB)
  const int tid = threadIdx.x;
  const int wave = tid >> 6, lane = tid & 63;
  const int q4 = lane >> 4, l16 = lane & 15;
  const int wm = wave >> 1, wn = wave & 1;
  const int bt0 = blockIdx.x * 64;
  const int cb0 = blockIdx.y * 192;

  const int arow16 = tid >> 4, agx = tid & 15;
  const int bcol32 = tid >> 3, bgx = tid & 7;

  const f32x4 zero4 = {0.f, 0.f, 0.f, 0.f};
  f32x4 acc[2][6];
#pragma unroll
  for (int mt = 0; mt < 2; ++mt)
#pragma unroll
    for (int nt = 0; nt < 6; ++nt) acc[mt][nt] = zero4;

  auto stage = [&](int bufi, int k0) {
#pragma unroll
    for (int i = 0; i < 4; ++i) {
      int row = i * 16 + arow16;
      gload16((char*)&ldsA[bufi][0] + i * 4096 + wave * 1024,
              x + (size_t)(bt0 + row) * C_ + k0 + ((agx ^ (row & 7)) << 2));
    }
#pragma unroll
    for (int i = 0; i < 6; ++i) {
      int col = i * 32 + bcol32;
      gload16((char*)&ldsB[bufi][0] + i * 4096 + wave * 1024,
              Wt + (size_t)(cb0 + col) * C_ + k0 + ((bgx ^ (col & 7)) << 3));
    }
  };

  stage(0, 0);
  __syncthreads();

  for (int it = 0; it < 16; ++it) {
    const int buf = it & 1;
    if (it + 1 < 16) stage(buf ^ 1, (it + 1) * 64);
#pragma unroll
    for (int kc = 0; kc < 2; ++kc) {
      bf16x8 af[2];
#pragma unroll
      for (int mt = 0; mt < 2; ++mt) {
        const int rl = wm * 32 + mt * 16 + l16;
        const int rx = rl & 7;
        fv4 a0 = *(const fv4*)&ldsA[buf][rl * 64 + (((kc * 8 + q4 * 2 + 0) ^ rx) << 2)];
        fv4 a1 = *(const fv4*)&ldsA[buf][rl * 64 + (((kc * 8 + q4 * 2 + 1) ^ rx) << 2)];
#pragma unroll
        for (int j = 0; j < 4; ++j) { af[mt][j] = (__bf16)a0[j]; af[mt][4 + j] = (__bf16)a1[j]; }
      }
#pragma unroll
      for (int nt = 0; nt < 6; ++nt) {
        const int cl = wn * 96 + nt * 16 + l16;
        bf16x8 bf = *(const bf16x8*)&ldsB[buf][cl * 64 + (((kc * 4 + q4) ^ (cl & 7)) << 3)];
#pragma unroll
        for (int mt = 0; mt < 2; ++mt)
          acc[mt][nt] = __builtin_amdgcn_mfma_f32_16x16x32_bf16(af[mt], bf, acc[mt][nt], 0, 0, 0);
      }
    }
    __syncthreads();
  }

  // epilogue. C/D: row=q4*4+r, col=l16 (HW-validated convention)
  const int b = bt0 >> 11, t0 = bt0 & (T_ - 1);
  __bf16* ldsV = (__bf16*)&ldsB[0][0];
#pragma unroll
  for (int mt = 0; mt < 2; ++mt)
#pragma unroll
    for (int nt = 0; nt < 6; ++nt) {
      int gcol = cb0 + wn * 96 + nt * 16 + l16;
#pragma unroll
      for (int r = 0; r < 4; ++r) {
        int tl = wm * 32 + mt * 16 + q4 * 4 + r;
        float v = acc[mt][nt][r];
        if (gcol < 128) Qw[(size_t)(bt0 + tl) * H_ + gcol] = (__bf16)v;
        else if (gcol < 256) Kw[(size_t)(bt0 + tl) * H_ + (gcol - 128)] = (__bf16)v;
        else ldsV[(gcol - 256) * 72 + tl] = (__bf16)v;
      }
    }
  if (cb0 == 192) {
    __syncthreads();
#pragma unroll
    for (int i = 0; i < 4; ++i) {
      int idx = tid + 256 * i;
      int h = idx >> 3, t8 = (idx & 7) << 3;
      *(bf16x8*)(Vtw + ((size_t)b * H_ + h) * T_ + t0 + t8) =
          *(const bf16x8*)&ldsV[h * 72 + t8];
    }
  }
}

// ---------------- split-K causal flash attention + fused last-block combine ----------
// grid (80, 8), block 256. Chunk = (qb, c): q-rows [qb*64,+64), KV tiles
// [8c, min(8c+8, qb+1)). Max-free softmax => partials combine exactly.
// Partial O stored bf16. The LAST-arriving chunk per (b,qb) (device-scope atomic
// counter, release/acquire via __threadfence) performs the combine -> removes the
// separate attn_combine dispatch. Arithmetic identical (cc loop ascending).
__global__ __launch_bounds__(256) void attn_split(
    const __bf16* __restrict__ Q, const __bf16* __restrict__ K,
    const __bf16* __restrict__ Vt, __bf16* __restrict__ PO,
    float* __restrict__ Pl, int* __restrict__ Cnt, float* __restrict__ out)
{
  __shared__ __align__(16) __bf16 ldsK[64 * 136];
  __shared__ __align__(16) __bf16 ldsV[128 * 72];
  __shared__ __align__(16) __bf16 ldsP[4][16 * 72];
  __shared__ int sprev;
  const int tid = threadIdx.x;
  const int wave = tid >> 6, lane = tid & 63;
  const int q4 = lane >> 4, l16 = lane & 15;
  const int b = blockIdx.y;
  int rem = blockIdx.x, qb = 0;
  while (rem >= (qb >> 3) + 1) { rem -= (qb >> 3) + 1; ++qb; }
  const int c = rem;
  const int tstart = c << 3;
  const int tend = min(tstart + 8, qb + 1);
  const int nch = (qb >> 3) + 1;
  const int qw = qb * 64 + wave * 16;
  const __bf16* Qb = Q + (size_t)b * T_ * H_;
  const __bf16* Kb = K + (size_t)b * T_ * H_;
  const __bf16* Vb = Vt + (size_t)b * H_ * T_;
  __bf16* ldsPw = &ldsP[wave][0];

  bf16x8 qf[4];
#pragma unroll
  for (int kc = 0; kc < 4; ++kc)
    qf[kc] = *(const bf16x8*)(Qb + (size_t)(qw + l16) * H_ + kc * 32 + q4 * 8);

  const f32x4 zero4 = {0.f, 0.f, 0.f, 0.f};
  f32x4 o[8];
#pragma unroll
  for (int nt = 0; nt < 8; ++nt) o[nt] = zero4;
  float lsum[4] = {0.f, 0.f, 0.f, 0.f};

  bf16x8 kp[4], vp[4];
#pragma unroll
  for (int i = 0; i < 4; ++i) {
    int idx = tid + 256 * i;
    int krow = idx >> 4, kcol8 = (idx & 15) << 3;
    kp[i] = *(const bf16x8*)(Kb + (size_t)(tstart * 64 + krow) * H_ + kcol8);
    int vrow = idx >> 3, vcol8 = (idx & 7) << 3;
    vp[i] = *(const bf16x8*)(Vb + (size_t)vrow * T_ + tstart * 64 + vcol8);
  }

  for (int t = tstart; t < tend; ++t) {
    const int kv0 = t << 6;
#pragma unroll
    for (int i = 0; i < 4; ++i) {
      int idx = tid + 256 * i;
      int krow = idx >> 4, kcol8 = (idx & 15) << 3;
      *(bf16x8*)&ldsK[krow * 136 + kcol8] = kp[i];
      int vrow = idx >> 3, vcol8 = (idx & 7) << 3;
      *(bf16x8*)&ldsV[vrow * 72 + vcol8] = vp[i];
    }
    __syncthreads();
    const int kvn = (t + 1 < tend) ? (kv0 + 64) : kv0;
#pragma unroll
    for (int i = 0; i < 4; ++i) {
      int idx = tid + 256 * i;
      int krow = idx >> 4, kcol8 = (idx & 15) << 3;
      kp[i] = *(const bf16x8*)(Kb + (size_t)(kvn + krow) * H_ + kcol8);
      int vrow = idx >> 3, vcol8 = (idx & 7) << 3;
      vp[i] = *(const bf16x8*)(Vb + (size_t)vrow * T_ + kvn + vcol8);
    }

    f32x4 s[4];
#pragma unroll
    for (int nt = 0; nt < 4; ++nt) s[nt] = zero4;
#pragma unroll
    for (int nt = 0; nt < 4; ++nt)
#pragma unroll
      for (int kc = 0; kc < 4; ++kc) {
        bf16x8 kf = *(const bf16x8*)&ldsK[(nt * 16 + l16) * 136 + kc * 32 + q4 * 8];
        s[nt] = __builtin_amdgcn_mfma_f32_16x16x32_bf16(qf[kc], kf, s[nt], 0, 0, 0);
      }

    if (t == qb) {
#pragma unroll
      for (int r = 0; r < 4; ++r) {
        const int grow = qw + q4 * 4 + r;
#pragma unroll
        for (int nt = 0; nt < 4; ++nt) {
          int col = kv0 + nt * 16 + l16;
          float p = (col <= grow) ? __expf(s[nt][r] * 0.08838834764831845f) : 0.f;
          lsum[r] += p;
          ldsPw[(q4 * 4 + r) * 72 + nt * 16 + l16] = (__bf16)p;
        }
      }
    } else {
#pragma unroll
      for (int r = 0; r < 4; ++r)
#pragma unroll
        for (int nt = 0; nt < 4; ++nt) {
          float p = __expf(s[nt][r] * 0.08838834764831845f);
          lsum[r] += p;
          ldsPw[(q4 * 4 + r) * 72 + nt * 16 + l16] = (__bf16)p;
        }
    }
#pragma unroll
    for (int kc2 = 0; kc2 < 2; ++kc2) {
      bf16x8 pf = *(const bf16x8*)&ldsPw[l16 * 72 + kc2 * 32 + q4 * 8];
#pragma unroll
      for (int nt = 0; nt < 8; ++nt) {
        bf16x8 vf = *(const bf16x8*)&ldsV[(nt * 16 + l16) * 72 + kc2 * 32 + q4 * 8];
        o[nt] = __builtin_amdgcn_mfma_f32_16x16x32_bf16(pf, vf, o[nt], 0, 0, 0);
      }
    }
    __syncthreads();
  }

  float lred[4];
#pragma unroll
  for (int r = 0; r < 4; ++r) {
    float l = lsum[r];
    l += __shfl_xor(l, 1);
    l += __shfl_xor(l, 2);
    l += __shfl_xor(l, 4);
    l += __shfl_xor(l, 8);
    lred[r] = l;
  }

  if (nch == 1) {
#pragma unroll
    for (int r = 0; r < 4; ++r) lred[r] = 1.f / lred[r];
#pragma unroll
    for (int nt = 0; nt < 8; ++nt)
#pragma unroll
      for (int r = 0; r < 4; ++r) {
        int row = qw + q4 * 4 + r;
        out[((size_t)b * T_ + row) * H_ + nt * 16 + l16] = o[nt][r] * lred[r];
      }
  } else {
    const int slot0 = b * 80 + qb + max(qb - 8, 0) + max(qb - 16, 0) + max(qb - 24, 0);
    const int slot = slot0 + c;
    __bf16* POs = PO + (size_t)slot * 8192;
#pragma unroll
    for (int nt = 0; nt < 8; ++nt)
#pragma unroll
      for (int r = 0; r < 4; ++r)
        POs[(wave * 16 + q4 * 4 + r) * 128 + nt * 16 + l16] = (__bf16)o[nt][r];
    if (l16 == 0)
#pragma unroll
      for (int r = 0; r < 4; ++r)
        Pl[slot * 64 + wave * 16 + q4 * 4 + r] = lred[r];

    // ---- last-arriving chunk combines (release: fence+barrier, then atomic) ----
    __threadfence();
    __syncthreads();
    if (tid == 0) sprev = atomicAdd(&Cnt[b * 32 + qb], 1);
    __syncthreads();
    if (sprev == nch - 1) {
      __threadfence();  // acquire other chunks' PO/Pl writes
      const int row = tid >> 2;          // 0..63
      const int cs = (tid & 3) << 5;     // 0,32,64,96
      float lacc = 0.f;
      float oc[32];
#pragma unroll
      for (int j = 0; j < 32; ++j) oc[j] = 0.f;
      for (int cc = 0; cc < nch; ++cc) {
        const int s2 = slot0 + cc;
        lacc += Pl[s2 * 64 + row];
        const __bf16* pp = PO + (size_t)s2 * 8192 + row * 128 + cs;
#pragma unroll
        for (int g = 0; g < 4; ++g) {
          bf16x8 v = *(const bf16x8*)(pp + g * 8);
#pragma unroll
          for (int j = 0; j < 8; ++j) oc[g * 8 + j] += (float)v[j];
        }
      }
      const float inv = 1.f / lacc;
      float* op = out + ((size_t)b * T_ + qb * 64 + row) * H_ + cs;
#pragma unroll
      for (int g = 0; g < 8; ++g) {
        fv4 v;
#pragma unroll
        for (int j = 0; j < 4; ++j) v[j] = oc[g * 4 + j] * inv;
        *(fv4*)(op + g * 4) = v;
      }
    }
  }
}

// ---------------- fallback mono attention (round-7, HW-validated) ----------------
__global__ __launch_bounds__(256) void attn_mono(
    const __bf16* __restrict__ Q, const __bf16* __restrict__ K,
    const __bf16* __restrict__ Vt, float* __restrict__ out)
{
  __shared__ __align__(16) __bf16 ldsK[64 * 136];
  __shared__ __align__(16) __bf16 ldsV[128 * 72];
  __shared__ __align__(16) __bf16 ldsP[4][16 * 72];
  const int tid = threadIdx.x;
  const int wave = tid >> 6, lane = tid & 63;
  const int q4 = lane >> 4, l16 = lane & 15;
  const int qb = blockIdx.x, b = blockIdx.y;
  const int qw = qb * 64 + wave * 16;
  const __bf16* Qb = Q + (size_t)b * T_ * H_;
  const __bf16* Kb = K + (size_t)b * T_ * H_;
  const __bf16* Vb = Vt + (size_t)b * H_ * T_;
  __bf16* ldsPw = &ldsP[wave][0];

  bf16x8 qf[4];
#pragma unroll
  for (int kc = 0; kc < 4; ++kc)
    qf[kc] = *(const bf16x8*)(Qb + (size_t)(qw + l16) * H_ + kc * 32 + q4 * 8);

  const f32x4 zero4 = {0.f, 0.f, 0.f, 0.f};
  f32x4 o[8];
#pragma unroll
  for (int nt = 0; nt < 8; ++nt) o[nt] = zero4;
  float lsum[4] = {0.f, 0.f, 0.f, 0.f};
  const int ntile = qb + 1;

  bf16x8 kp[4], vp[4];
#pragma unroll
  for (int i = 0; i < 4; ++i) {
    int idx = tid + 256 * i;
    int krow = idx >> 4, kcol8 = (idx & 15) << 3;
    kp[i] = *(const bf16x8*)(Kb + (size_t)krow * H_ + kcol8);
    int vrow = idx >> 3, vcol8 = (idx & 7) << 3;
    vp[i] = *(const bf16x8*)(Vb + (size_t)vrow * T_ + vcol8);
  }

  for (int t = 0; t < ntile; ++t) {
    const int kv0 = t << 6;
#pragma unroll
    for (int i = 0; i < 4; ++i) {
      int idx = tid + 256 * i;
      int krow = idx >> 4, kcol8 = (idx & 15) << 3;
      *(bf16x8*)&ldsK[krow * 136 + kcol8] = kp[i];
      int vrow = idx >> 3, vcol8 = (idx & 7) << 3;
      *(bf16x8*)&ldsV[vrow * 72 + vcol8] = vp[i];
    }
    __syncthreads();
    int kvn = (t + 1 < ntile) ? (kv0 + 64) : kv0;
#pragma unroll
    for (int i = 0; i < 4; ++i) {
      int idx = tid + 256 * i;
      int krow = idx >> 4, kcol8 = (idx & 15) << 3;
      kp[i] = *(const bf16x8*)(Kb + (size_t)(kvn + krow) * H_ + kcol8);
      int vrow = idx >> 3, vcol8 = (idx & 7) << 3;
      vp[i] = *(const bf16x8*)(Vb + (size_t)vrow * T_ + kvn + vcol8);
    }
    f32x4 s[4];
#pragma unroll
    for (int nt = 0; nt < 4; ++nt) s[nt] = zero4;
#pragma unroll
    for (int nt = 0; nt < 4; ++nt)
#pragma unroll
      for (int kc = 0; kc < 4; ++kc) {
        bf16x8 kf = *(const bf16x8*)&ldsK[(nt * 16 + l16) * 136 + kc * 32 + q4 * 8];
        s[nt] = __builtin_amdgcn_mfma_f32_16x16x32_bf16(qf[kc], kf, s[nt], 0, 0, 0);
      }
#pragma unroll
    for (int r = 0; r < 4; ++r) {
      const int grow = qw + q4 * 4 + r;
#pragma unroll
      for (int nt = 0; nt < 4; ++nt) {
        int col = kv0 + nt * 16 + l16;
        float p = (col <= grow) ? __expf(s[nt][r] * 0.08838834764831845f) : 0.f;
        lsum[r] += p;
        ldsPw[(q4 * 4 + r) * 72 + nt * 16 + l16] = (__bf16)p;
      }
    }
#pragma unroll
    for (int kc2 = 0; kc2 < 2; ++kc2) {
      bf16x8 pf = *(const bf16x8*)&ldsPw[l16 * 72 + kc2 * 32 + q4 * 8];
#pragma unroll
      for (int nt = 0; nt < 8; ++nt) {
        bf16x8 vf = *(const bf16x8*)&ldsV[(nt * 16 + l16) * 72 + kc2 * 32 + q4 * 8];
        o[nt] = __builtin_amdgcn_mfma_f32_16x16x32_bf16(pf, vf, o[nt], 0, 0, 0);
      }
    }
    __syncthreads();
  }
  float rinv[4];
#pragma unroll
  for (int r = 0; r < 4; ++r) {
    float l = lsum[r];
    l += __shfl_xor(l, 1);
    l += __shfl_xor(l, 2);
    l += __shfl_xor(l, 4);
    l += __shfl_xor(l, 8);
    rinv[r] = 1.f / l;
  }
#pragma unroll
  for (int nt = 0; nt < 8; ++nt)
#pragma unroll
    for (int r = 0; r < 4; ++r) {
      int row = qw + q4 * 4 + r;
      out[((size_t)b * T_ + row) * H_ + nt * 16 + l16] = o[nt][r] * rinv[r];
    }
}

extern "C" void kernel_launch(void* const* d_in, const int* in_sizes, int n_in,
                              void* d_out, int out_size, void* d_ws, size_t ws_size,
                              hipStream_t stream) {
  const float* x  = (const float*)d_in[0];
  const float* Wq = (const float*)d_in[1];
  const float* Wk = (const float*)d_in[2];
  const float* Wv = (const float*)d_in[3];
  __bf16* ws = (__bf16*)d_ws;
  __bf16* Qw  = ws;                             // [B*T][H]   4 MB
  __bf16* Kw  = ws + (size_t)B_ * T_ * H_;      // [B*T][H]   4 MB
  __bf16* Vtw = ws + (size_t)2 * B_ * T_ * H_;  // [B][H][T]  4 MB
  __bf16* Wt  = ws + (size_t)3 * B_ * T_ * H_;  // [3][H][C]  0.75 MB
  const size_t bf16_elems = 6684672;            // 13,369,344 B
  __bf16* PO = ws + bf16_elems;                 // 640 x 8192 bf16 = 10.5 MB
  float* Pl = (float*)(ws + bf16_elems + (size_t)640 * 8192);  // 640 x 64 fp32
  int* Cnt = (int*)(Pl + 640 * 64);             // 256 arrival counters
  const size_t need = bf16_elems * 2 + (size_t)640 * 8192 * 2 + (size_t)640 * 64 * 4 + 1024;
  float* out = (float*)d_out;

  const bool split = ws_size >= need;
  prep_kernel<<<dim3(8, 3), 256, 0, stream>>>(Wq, Wk, Wv, Wt, split ? Cnt : (int*)nullptr);
  proj_kernel<<<dim3(256, 2), 256, 0, stream>>>(x, Wt, Qw, Kw, Vtw);
  if (split) {
    attn_split<<<dim3(80, 8), 256, 0, stream>>>(Qw, Kw, Vtw, PO, Pl, Cnt, out);
  } else {
    attn_mono<<<dim3(32, 8), 256, 0, stream>>>(Qw, Kw, Vtw, out);
  }
}

// Round 3
// 158.490 us; speedup vs baseline: 1.6522x; 1.6522x over previous
//
#include <hip/hip_runtime.h>

typedef __bf16 bf16x8 __attribute__((ext_vector_type(8)));
typedef float f32x4 __attribute__((ext_vector_type(4)));
typedef float fv4 __attribute__((ext_vector_type(4)));

#define B_ 8
#define T_ 2048
#define C_ 1024
#define H_ 128

// async global->LDS, 16B per lane. LDS dest = wave-uniform base + lane*16.
__device__ __forceinline__ void gload16(void* lds, const void* g) {
  __builtin_amdgcn_global_load_lds(
      (const __attribute__((address_space(1))) void*)g,
      (__attribute__((address_space(3))) void*)lds, 16, 0, 0);
}

// ROUND-2 LESSON (kept as a guard): do NOT fuse the split-K combine via device-scope
// atomics/__threadfence. Per-XCD L2s are non-coherent; each release fence forces an
// L2 writeback -> 640 blocks serialize (attn_split 40 -> 160 us measured). The
// separate combine dispatch is far cheaper.

// ---------------- prep: W[1024][128] fp32 -> Wt[wsel][128][1024] bf16 ----------------
__global__ __launch_bounds__(256) void prep_kernel(
    const float* __restrict__ Wq, const float* __restrict__ Wk,
    const float* __restrict__ Wv, __bf16* __restrict__ Wt)
{
  __shared__ __bf16 ldsT[128 * 136];
  const int tid = threadIdx.x;
  const int k0 = blockIdx.x * 128;
  const int wsel = blockIdx.y;
  const float* W = wsel == 0 ? Wq : (wsel == 1 ? Wk : Wv);
#pragma unroll
  for (int i = 0; i < 16; ++i) {
    int fidx = tid + 256 * i;
    int k = fidx >> 5, h4 = (fidx & 31) << 2;
    fv4 w = *(const fv4*)(W + (size_t)(k0 + k) * H_ + h4);
#pragma unroll
    for (int j = 0; j < 4; ++j) ldsT[(h4 + j) * 136 + k] = (__bf16)w[j];
  }
  __syncthreads();
#pragma unroll
  for (int i = 0; i < 8; ++i) {
    int sidx = tid + 256 * i;
    int h = sidx >> 4, c8 = (sidx & 15) << 3;
    *(bf16x8*)(Wt + (size_t)wsel * H_ * C_ + (size_t)h * C_ + k0 + c8) =
        *(const bf16x8*)&ldsT[h * 136 + c8];
  }
}

// ---------------- fused QKV projection (round-1, HW-validated) ----------------------
// GEMM M=16384 N=384 K=1024. Block = 64 rows x 192 cols, grid (256,2) -> 2 blocks/CU.
// global_load_lds DMA staging, one barrier per K-step, rule-21 XOR swizzle.
__global__ __launch_bounds__(256) void proj_kernel(
    const float* __restrict__ x, const __bf16* __restrict__ Wt,
    __bf16* __restrict__ Qw, __bf16* __restrict__ Kw, __bf16* __restrict__ Vtw)
{
  __shared__ __align__(16) float ldsA[2][64 * 64];     // 2 x 16 KB
  __shared__ __align__(16) __bf16 ldsB[2][192 * 64];   // 2 x 24 KB  (total 80 KB)
  const int tid = threadIdx.x;
  const int wave = tid >> 6, lane = tid & 63;
  const int q4 = lane >> 4, l16 = lane & 15;
  const int wm = wave >> 1, wn = wave & 1;
  const int bt0 = blockIdx.x * 64;
  const int cb0 = blockIdx.y * 192;

  const int arow16 = tid >> 4, agx = tid & 15;
  const int bcol32 = tid >> 3, bgx = tid & 7;

  const f32x4 zero4 = {0.f, 0.f, 0.f, 0.f};
  f32x4 acc[2][6];
#pragma unroll
  for (int mt = 0; mt < 2; ++mt)
#pragma unroll
    for (int nt = 0; nt < 6; ++nt) acc[mt][nt] = zero4;

  auto stage = [&](int bufi, int k0) {
#pragma unroll
    for (int i = 0; i < 4; ++i) {
      int row = i * 16 + arow16;
      gload16((char*)&ldsA[bufi][0] + i * 4096 + wave * 1024,
              x + (size_t)(bt0 + row) * C_ + k0 + ((agx ^ (row & 7)) << 2));
    }
#pragma unroll
    for (int i = 0; i < 6; ++i) {
      int col = i * 32 + bcol32;
      gload16((char*)&ldsB[bufi][0] + i * 4096 + wave * 1024,
              Wt + (size_t)(cb0 + col) * C_ + k0 + ((bgx ^ (col & 7)) << 3));
    }
  };

  stage(0, 0);
  __syncthreads();

  for (int it = 0; it < 16; ++it) {
    const int buf = it & 1;
    if (it + 1 < 16) stage(buf ^ 1, (it + 1) * 64);
#pragma unroll
    for (int kc = 0; kc < 2; ++kc) {
      bf16x8 af[2];
#pragma unroll
      for (int mt = 0; mt < 2; ++mt) {
        const int rl = wm * 32 + mt * 16 + l16;
        const int rx = rl & 7;
        fv4 a0 = *(const fv4*)&ldsA[buf][rl * 64 + (((kc * 8 + q4 * 2 + 0) ^ rx) << 2)];
        fv4 a1 = *(const fv4*)&ldsA[buf][rl * 64 + (((kc * 8 + q4 * 2 + 1) ^ rx) << 2)];
#pragma unroll
        for (int j = 0; j < 4; ++j) { af[mt][j] = (__bf16)a0[j]; af[mt][4 + j] = (__bf16)a1[j]; }
      }
#pragma unroll
      for (int nt = 0; nt < 6; ++nt) {
        const int cl = wn * 96 + nt * 16 + l16;
        bf16x8 bf = *(const bf16x8*)&ldsB[buf][cl * 64 + (((kc * 4 + q4) ^ (cl & 7)) << 3)];
#pragma unroll
        for (int mt = 0; mt < 2; ++mt)
          acc[mt][nt] = __builtin_amdgcn_mfma_f32_16x16x32_bf16(af[mt], bf, acc[mt][nt], 0, 0, 0);
      }
    }
    __syncthreads();
  }

  // epilogue. C/D: row=q4*4+r, col=l16 (HW-validated convention)
  const int b = bt0 >> 11, t0 = bt0 & (T_ - 1);
  __bf16* ldsV = (__bf16*)&ldsB[0][0];
#pragma unroll
  for (int mt = 0; mt < 2; ++mt)
#pragma unroll
    for (int nt = 0; nt < 6; ++nt) {
      int gcol = cb0 + wn * 96 + nt * 16 + l16;
#pragma unroll
      for (int r = 0; r < 4; ++r) {
        int tl = wm * 32 + mt * 16 + q4 * 4 + r;
        float v = acc[mt][nt][r];
        if (gcol < 128) Qw[(size_t)(bt0 + tl) * H_ + gcol] = (__bf16)v;
        else if (gcol < 256) Kw[(size_t)(bt0 + tl) * H_ + (gcol - 128)] = (__bf16)v;
        else ldsV[(gcol - 256) * 72 + tl] = (__bf16)v;
      }
    }
  if (cb0 == 192) {
    __syncthreads();
#pragma unroll
    for (int i = 0; i < 4; ++i) {
      int idx = tid + 256 * i;
      int h = idx >> 3, t8 = (idx & 7) << 3;
      *(bf16x8*)(Vtw + ((size_t)b * H_ + h) * T_ + t0 + t8) =
          *(const bf16x8*)&ldsV[h * 72 + t8];
    }
  }
}

// ---------------- split-K causal flash attention, v2: DMA-staged K/V ----------------
// grid (80, 8), block 256. Chunk = (qb, c): q-rows [qb*64,+64), KV tiles
// [8c, min(8c+8, qb+1)). Max-free softmax => partials combine exactly.
// K[64][128] and Vt[128][64] staged via global_load_lds, double-buffered, ONE
// barrier per tile (proj's proven structure). Rule-21 swizzle: LDS linear,
// global source granule ^= (row&7), ds_read applies same XOR -> 2-way = free.
__global__ __launch_bounds__(256) void attn_split(
    const __bf16* __restrict__ Q, const __bf16* __restrict__ K,
    const __bf16* __restrict__ Vt, __bf16* __restrict__ PO,
    float* __restrict__ Pl, float* __restrict__ out)
{
  __shared__ __align__(16) __bf16 ldsK[2][64 * 128];   // 2 x 16 KB
  __shared__ __align__(16) __bf16 ldsV[2][128 * 64];   // 2 x 16 KB
  __shared__ __align__(16) __bf16 ldsP[4][16 * 72];    // 9 KB (73 KB total -> 2 blk/CU)
  const int tid = threadIdx.x;
  const int wave = tid >> 6, lane = tid & 63;
  const int q4 = lane >> 4, l16 = lane & 15;
  const int b = blockIdx.y;
  int rem = blockIdx.x, qb = 0;
  while (rem >= (qb >> 3) + 1) { rem -= (qb >> 3) + 1; ++qb; }
  const int c = rem;
  const int tstart = c << 3;
  const int tend = min(tstart + 8, qb + 1);
  const int nch = (qb >> 3) + 1;
  const int qw = qb * 64 + wave * 16;
  const __bf16* Qb = Q + (size_t)b * T_ * H_;
  const __bf16* Kb = K + (size_t)b * T_ * H_;
  const __bf16* Vb = Vt + (size_t)b * H_ * T_;
  __bf16* ldsPw = &ldsP[wave][0];

  bf16x8 qf[4];
#pragma unroll
  for (int kc = 0; kc < 4; ++kc)
    qf[kc] = *(const bf16x8*)(Qb + (size_t)(qw + l16) * H_ + kc * 32 + q4 * 8);

  const f32x4 zero4 = {0.f, 0.f, 0.f, 0.f};
  f32x4 o[8];
#pragma unroll
  for (int nt = 0; nt < 8; ++nt) o[nt] = zero4;
  float lsum[4] = {0.f, 0.f, 0.f, 0.f};

  // DMA staging: K granule idx = krow*16+kg (16B granules), V idx = vrow*8+vg.
  auto stageKV = [&](int bufi, int t) {
    const int kv0 = t << 6;
#pragma unroll
    for (int i = 0; i < 4; ++i) {
      int kr = i * 16 + (tid >> 4);
      gload16((char*)&ldsK[bufi][0] + i * 4096 + wave * 1024,
              Kb + (size_t)(kv0 + kr) * H_ + (((tid & 15) ^ (kr & 7)) << 3));
      int vr = i * 32 + (tid >> 3);
      gload16((char*)&ldsV[bufi][0] + i * 4096 + wave * 1024,
              Vb + (size_t)vr * T_ + kv0 + (((tid & 7) ^ (vr & 7)) << 3));
    }
  };

  stageKV(0, tstart);
  __syncthreads();  // vmcnt(0) drain: buf0 ready

  for (int t = tstart; t < tend; ++t) {
    const int buf = (t - tstart) & 1;
    const int kv0 = t << 6;
    if (t + 1 < tend) stageKV(buf ^ 1, t + 1);  // issue DMA before compute

    f32x4 s[4];
#pragma unroll
    for (int nt = 0; nt < 4; ++nt) s[nt] = zero4;
#pragma unroll
    for (int nt = 0; nt < 4; ++nt) {
      const int krow = nt * 16 + l16;
      const int kx = krow & 7;
#pragma unroll
      for (int kc = 0; kc < 4; ++kc) {
        bf16x8 kf = *(const bf16x8*)&ldsK[buf][krow * 128 + (((kc * 4 + q4) ^ kx) << 3)];
        s[nt] = __builtin_amdgcn_mfma_f32_16x16x32_bf16(qf[kc], kf, s[nt], 0, 0, 0);
      }
    }

    if (t == qb) {
#pragma unroll
      for (int r = 0; r < 4; ++r) {
        const int grow = qw + q4 * 4 + r;
#pragma unroll
        for (int nt = 0; nt < 4; ++nt) {
          int col = kv0 + nt * 16 + l16;
          float p = (col <= grow) ? __expf(s[nt][r] * 0.08838834764831845f) : 0.f;
          lsum[r] += p;
          ldsPw[(q4 * 4 + r) * 72 + nt * 16 + l16] = (__bf16)p;
        }
      }
    } else {
#pragma unroll
      for (int r = 0; r < 4; ++r)
#pragma unroll
        for (int nt = 0; nt < 4; ++nt) {
          float p = __expf(s[nt][r] * 0.08838834764831845f);
          lsum[r] += p;
          ldsPw[(q4 * 4 + r) * 72 + nt * 16 + l16] = (__bf16)p;
        }
    }
#pragma unroll
    for (int kc2 = 0; kc2 < 2; ++kc2) {
      bf16x8 pf = *(const bf16x8*)&ldsPw[l16 * 72 + kc2 * 32 + q4 * 8];
#pragma unroll
      for (int nt = 0; nt < 8; ++nt) {
        const int vrow = nt * 16 + l16;
        bf16x8 vf = *(const bf16x8*)&ldsV[buf][vrow * 64 + (((kc2 * 4 + q4) ^ (vrow & 7)) << 3)];
        o[nt] = __builtin_amdgcn_mfma_f32_16x16x32_bf16(pf, vf, o[nt], 0, 0, 0);
      }
    }
    __syncthreads();  // one barrier/tile: next-tile DMA landed + this buf's reads done
  }

  float lred[4];
#pragma unroll
  for (int r = 0; r < 4; ++r) {
    float l = lsum[r];
    l += __shfl_xor(l, 1);
    l += __shfl_xor(l, 2);
    l += __shfl_xor(l, 4);
    l += __shfl_xor(l, 8);
    lred[r] = l;
  }

  if (nch == 1) {
#pragma unroll
    for (int r = 0; r < 4; ++r) lred[r] = 1.f / lred[r];
#pragma unroll
    for (int nt = 0; nt < 8; ++nt)
#pragma unroll
      for (int r = 0; r < 4; ++r) {
        int row = qw + q4 * 4 + r;
        out[((size_t)b * T_ + row) * H_ + nt * 16 + l16] = o[nt][r] * lred[r];
      }
  } else {
    const int slot = b * 80 + qb + max(qb - 8, 0) + max(qb - 16, 0) + max(qb - 24, 0) + c;
    __bf16* POs = PO + (size_t)slot * 8192;
#pragma unroll
    for (int nt = 0; nt < 8; ++nt)
#pragma unroll
      for (int r = 0; r < 4; ++r)
        POs[(wave * 16 + q4 * 4 + r) * 128 + nt * 16 + l16] = (__bf16)o[nt][r];
    if (l16 == 0)
#pragma unroll
      for (int r = 0; r < 4; ++r)
        Pl[slot * 64 + wave * 16 + q4 * 4 + r] = lred[r];
  }
}

// ---------------- combine partials (qb >= 8), 16 rows/block ----------------
__global__ __launch_bounds__(256) void attn_combine(
    const __bf16* __restrict__ PO, const float* __restrict__ Pl,
    float* __restrict__ out)
{
  const int qb = 8 + (blockIdx.x >> 2);
  const int seg = blockIdx.x & 3;
  const int b = blockIdx.y;
  const int nch = (qb >> 3) + 1;
  const int slot0 = b * 80 + qb + max(qb - 8, 0) + max(qb - 16, 0) + max(qb - 24, 0);
  const int tid = threadIdx.x;
  const int rloc = seg * 16 + (tid >> 4);   // row within qb block
  const int col8 = (tid & 15) << 3;
  float oacc[8] = {0.f};
  float lacc = 0.f;
  for (int cc = 0; cc < nch; ++cc) {
    const int slot = slot0 + cc;
    lacc += Pl[slot * 64 + rloc];
    bf16x8 v = *(const bf16x8*)(PO + (size_t)slot * 8192 + rloc * 128 + col8);
#pragma unroll
    for (int j = 0; j < 8; ++j) oacc[j] += (float)v[j];
  }
  const float inv = 1.f / lacc;
  float* op = out + ((size_t)b * T_ + qb * 64 + rloc) * H_ + col8;
  fv4 v0, v1;
#pragma unroll
  for (int j = 0; j < 4; ++j) { v0[j] = oacc[j] * inv; v1[j] = oacc[4 + j] * inv; }
  *(fv4*)op = v0;
  *(fv4*)(op + 4) = v1;
}

// ---------------- fallback mono attention (round-7, HW-validated) ----------------
__global__ __launch_bounds__(256) void attn_mono(
    const __bf16* __restrict__ Q, const __bf16* __restrict__ K,
    const __bf16* __restrict__ Vt, float* __restrict__ out)
{
  __shared__ __align__(16) __bf16 ldsK[64 * 136];
  __shared__ __align__(16) __bf16 ldsV[128 * 72];
  __shared__ __align__(16) __bf16 ldsP[4][16 * 72];
  const int tid = threadIdx.x;
  const int wave = tid >> 6, lane = tid & 63;
  const int q4 = lane >> 4, l16 = lane & 15;
  const int qb = blockIdx.x, b = blockIdx.y;
  const int qw = qb * 64 + wave * 16;
  const __bf16* Qb = Q + (size_t)b * T_ * H_;
  const __bf16* Kb = K + (size_t)b * T_ * H_;
  const __bf16* Vb = Vt + (size_t)b * H_ * T_;
  __bf16* ldsPw = &ldsP[wave][0];

  bf16x8 qf[4];
#pragma unroll
  for (int kc = 0; kc < 4; ++kc)
    qf[kc] = *(const bf16x8*)(Qb + (size_t)(qw + l16) * H_ + kc * 32 + q4 * 8);

  const f32x4 zero4 = {0.f, 0.f, 0.f, 0.f};
  f32x4 o[8];
#pragma unroll
  for (int nt = 0; nt < 8; ++nt) o[nt] = zero4;
  float lsum[4] = {0.f, 0.f, 0.f, 0.f};
  const int ntile = qb + 1;

  bf16x8 kp[4], vp[4];
#pragma unroll
  for (int i = 0; i < 4; ++i) {
    int idx = tid + 256 * i;
    int krow = idx >> 4, kcol8 = (idx & 15) << 3;
    kp[i] = *(const bf16x8*)(Kb + (size_t)krow * H_ + kcol8);
    int vrow = idx >> 3, vcol8 = (idx & 7) << 3;
    vp[i] = *(const bf16x8*)(Vb + (size_t)vrow * T_ + vcol8);
  }

  for (int t = 0; t < ntile; ++t) {
    const int kv0 = t << 6;
#pragma unroll
    for (int i = 0; i < 4; ++i) {
      int idx = tid + 256 * i;
      int krow = idx >> 4, kcol8 = (idx & 15) << 3;
      *(bf16x8*)&ldsK[krow * 136 + kcol8] = kp[i];
      int vrow = idx >> 3, vcol8 = (idx & 7) << 3;
      *(bf16x8*)&ldsV[vrow * 72 + vcol8] = vp[i];
    }
    __syncthreads();
    int kvn = (t + 1 < ntile) ? (kv0 + 64) : kv0;
#pragma unroll
    for (int i = 0; i < 4; ++i) {
      int idx = tid + 256 * i;
      int krow = idx >> 4, kcol8 = (idx & 15) << 3;
      kp[i] = *(const bf16x8*)(Kb + (size_t)(kvn + krow) * H_ + kcol8);
      int vrow = idx >> 3, vcol8 = (idx & 7) << 3;
      vp[i] = *(const bf16x8*)(Vb + (size_t)vrow * T_ + kvn + vcol8);
    }
    f32x4 s[4];
#pragma unroll
    for (int nt = 0; nt < 4; ++nt) s[nt] = zero4;
#pragma unroll
    for (int nt = 0; nt < 4; ++nt)
#pragma unroll
      for (int kc = 0; kc < 4; ++kc) {
        bf16x8 kf = *(const bf16x8*)&ldsK[(nt * 16 + l16) * 136 + kc * 32 + q4 * 8];
        s[nt] = __builtin_amdgcn_mfma_f32_16x16x32_bf16(qf[kc], kf, s[nt], 0, 0, 0);
      }
#pragma unroll
    for (int r = 0; r < 4; ++r) {
      const int grow = qw + q4 * 4 + r;
#pragma unroll
      for (int nt = 0; nt < 4; ++nt) {
        int col = kv0 + nt * 16 + l16;
        float p = (col <= grow) ? __expf(s[nt][r] * 0.08838834764831845f) : 0.f;
        lsum[r] += p;
        ldsPw[(q4 * 4 + r) * 72 + nt * 16 + l16] = (__bf16)p;
      }
    }
#pragma unroll
    for (int kc2 = 0; kc2 < 2; ++kc2) {
      bf16x8 pf = *(const bf16x8*)&ldsPw[l16 * 72 + kc2 * 32 + q4 * 8];
#pragma unroll
      for (int nt = 0; nt < 8; ++nt) {
        bf16x8 vf = *(const bf16x8*)&ldsV[(nt * 16 + l16) * 72 + kc2 * 32 + q4 * 8];
        o[nt] = __builtin_amdgcn_mfma_f32_16x16x32_bf16(pf, vf, o[nt], 0, 0, 0);
      }
    }
    __syncthreads();
  }
  float rinv[4];
#pragma unroll
  for (int r = 0; r < 4; ++r) {
    float l = lsum[r];
    l += __shfl_xor(l, 1);
    l += __shfl_xor(l, 2);
    l += __shfl_xor(l, 4);
    l += __shfl_xor(l, 8);
    rinv[r] = 1.f / l;
  }
#pragma unroll
  for (int nt = 0; nt < 8; ++nt)
#pragma unroll
    for (int r = 0; r < 4; ++r) {
      int row = qw + q4 * 4 + r;
      out[((size_t)b * T_ + row) * H_ + nt * 16 + l16] = o[nt][r] * rinv[r];
    }
}

extern "C" void kernel_launch(void* const* d_in, const int* in_sizes, int n_in,
                              void* d_out, int out_size, void* d_ws, size_t ws_size,
                              hipStream_t stream) {
  const float* x  = (const float*)d_in[0];
  const float* Wq = (const float*)d_in[1];
  const float* Wk = (const float*)d_in[2];
  const float* Wv = (const float*)d_in[3];
  __bf16* ws = (__bf16*)d_ws;
  __bf16* Qw  = ws;                             // [B*T][H]   4 MB
  __bf16* Kw  = ws + (size_t)B_ * T_ * H_;      // [B*T][H]   4 MB
  __bf16* Vtw = ws + (size_t)2 * B_ * T_ * H_;  // [B][H][T]  4 MB
  __bf16* Wt  = ws + (size_t)3 * B_ * T_ * H_;  // [3][H][C]  0.75 MB
  const size_t bf16_elems = 6684672;            // 13,369,344 B
  __bf16* PO = ws + bf16_elems;                 // 640 x 8192 bf16 = 10.5 MB
  float* Pl = (float*)(ws + bf16_elems + (size_t)640 * 8192);  // 640 x 64 fp32
  const size_t need = bf16_elems * 2 + (size_t)640 * 8192 * 2 + (size_t)640 * 64 * 4;
  float* out = (float*)d_out;

  prep_kernel<<<dim3(8, 3), 256, 0, stream>>>(Wq, Wk, Wv, Wt);
  proj_kernel<<<dim3(256, 2), 256, 0, stream>>>(x, Wt, Qw, Kw, Vtw);
  if (ws_size >= need) {
    attn_split<<<dim3(80, 8), 256, 0, stream>>>(Qw, Kw, Vtw, PO, Pl, out);
    attn_combine<<<dim3(96, 8), 256, 0, stream>>>(PO, Pl, out);
  } else {
    attn_mono<<<dim3(32, 8), 256, 0, stream>>>(Qw, Kw, Vtw, out);
  }
}

// Round 4
// 157.687 us; speedup vs baseline: 1.6607x; 1.0051x over previous
//
#include <hip/hip_runtime.h>

typedef __bf16 bf16x8 __attribute__((ext_vector_type(8)));
typedef float f32x4 __attribute__((ext_vector_type(4)));
typedef float fv4 __attribute__((ext_vector_type(4)));

#define B_ 8
#define T_ 2048
#define C_ 1024
#define H_ 128

// async global->LDS, 16B per lane. LDS dest = wave-uniform base + lane*16.
__device__ __forceinline__ void gload16(void* lds, const void* g) {
  __builtin_amdgcn_global_load_lds(
      (const __attribute__((address_space(1))) void*)g,
      (__attribute__((address_space(3))) void*)lds, 16, 0, 0);
}

// ROUND-2 LESSON: do NOT fuse the split-K combine via device-scope atomics/fences
// (per-XCD L2 non-coherence made attn_split 40 -> 160 us). Separate dispatch is cheap.
// ROUND-4: counted-vmcnt pipeline (T4/m218): raw s_barrier + s_waitcnt vmcnt(G) keeps
// one stage-group in flight across barriers instead of draining it every iteration.

// ---------------- prep: W[1024][128] fp32 -> Wt[wsel][128][1024] bf16 ----------------
__global__ __launch_bounds__(256) void prep_kernel(
    const float* __restrict__ Wq, const float* __restrict__ Wk,
    const float* __restrict__ Wv, __bf16* __restrict__ Wt)
{
  __shared__ __bf16 ldsT[128 * 136];
  const int tid = threadIdx.x;
  const int k0 = blockIdx.x * 128;
  const int wsel = blockIdx.y;
  const float* W = wsel == 0 ? Wq : (wsel == 1 ? Wk : Wv);
#pragma unroll
  for (int i = 0; i < 16; ++i) {
    int fidx = tid + 256 * i;
    int k = fidx >> 5, h4 = (fidx & 31) << 2;
    fv4 w = *(const fv4*)(W + (size_t)(k0 + k) * H_ + h4);
#pragma unroll
    for (int j = 0; j < 4; ++j) ldsT[(h4 + j) * 136 + k] = (__bf16)w[j];
  }
  __syncthreads();
#pragma unroll
  for (int i = 0; i < 8; ++i) {
    int sidx = tid + 256 * i;
    int h = sidx >> 4, c8 = (sidx & 15) << 3;
    *(bf16x8*)(Wt + (size_t)wsel * H_ * C_ + (size_t)h * C_ + k0 + c8) =
        *(const bf16x8*)&ldsT[h * 136 + c8];
  }
}

// ---------------- fused QKV projection, v3: counted-vmcnt pipeline -----------------
// GEMM M=16384 N=384 K=1024. Block = 64 rows x 192 cols, grid (256,2) -> 2 blocks/CU.
// global_load_lds DMA staging (10 loads/thread/stage), rule-21 XOR swizzle.
// Per K-step: vmcnt(10) [tile t landed, t+1 stays in flight] -> barrier -> compute
// -> barrier -> issue stage(t+2). No vmcnt(0) drain in the main loop.
__global__ __launch_bounds__(256) void proj_kernel(
    const float* __restrict__ x, const __bf16* __restrict__ Wt,
    __bf16* __restrict__ Qw, __bf16* __restrict__ Kw, __bf16* __restrict__ Vtw)
{
  __shared__ __align__(16) float ldsA[2][64 * 64];     // 2 x 16 KB
  __shared__ __align__(16) __bf16 ldsB[2][192 * 64];   // 2 x 24 KB  (total 80 KB)
  const int tid = threadIdx.x;
  const int wave = tid >> 6, lane = tid & 63;
  const int q4 = lane >> 4, l16 = lane & 15;
  const int wm = wave >> 1, wn = wave & 1;
  const int bt0 = blockIdx.x * 64;
  const int cb0 = blockIdx.y * 192;

  const int arow16 = tid >> 4, agx = tid & 15;
  const int bcol32 = tid >> 3, bgx = tid & 7;

  const f32x4 zero4 = {0.f, 0.f, 0.f, 0.f};
  f32x4 acc[2][6];
#pragma unroll
  for (int mt = 0; mt < 2; ++mt)
#pragma unroll
    for (int nt = 0; nt < 6; ++nt) acc[mt][nt] = zero4;

  auto stage = [&](int bufi, int k0) {
#pragma unroll
    for (int i = 0; i < 4; ++i) {
      int row = i * 16 + arow16;
      gload16((char*)&ldsA[bufi][0] + i * 4096 + wave * 1024,
              x + (size_t)(bt0 + row) * C_ + k0 + ((agx ^ (row & 7)) << 2));
    }
#pragma unroll
    for (int i = 0; i < 6; ++i) {
      int col = i * 32 + bcol32;
      gload16((char*)&ldsB[bufi][0] + i * 4096 + wave * 1024,
              Wt + (size_t)(cb0 + col) * C_ + k0 + ((bgx ^ (col & 7)) << 3));
    }
  };

  stage(0, 0);
  stage(1, 64);  // 20 loads in flight

  for (int it = 0; it < 16; ++it) {
    const int buf = it & 1;
    if (it < 15) asm volatile("s_waitcnt vmcnt(10)" ::: "memory");
    else         asm volatile("s_waitcnt vmcnt(0)" ::: "memory");
    __builtin_amdgcn_sched_barrier(0);
    __builtin_amdgcn_s_barrier();
    __builtin_amdgcn_sched_barrier(0);
#pragma unroll
    for (int kc = 0; kc < 2; ++kc) {
      bf16x8 af[2];
#pragma unroll
      for (int mt = 0; mt < 2; ++mt) {
        const int rl = wm * 32 + mt * 16 + l16;
        const int rx = rl & 7;
        fv4 a0 = *(const fv4*)&ldsA[buf][rl * 64 + (((kc * 8 + q4 * 2 + 0) ^ rx) << 2)];
        fv4 a1 = *(const fv4*)&ldsA[buf][rl * 64 + (((kc * 8 + q4 * 2 + 1) ^ rx) << 2)];
#pragma unroll
        for (int j = 0; j < 4; ++j) { af[mt][j] = (__bf16)a0[j]; af[mt][4 + j] = (__bf16)a1[j]; }
      }
#pragma unroll
      for (int nt = 0; nt < 6; ++nt) {
        const int cl = wn * 96 + nt * 16 + l16;
        bf16x8 bf = *(const bf16x8*)&ldsB[buf][cl * 64 + (((kc * 4 + q4) ^ (cl & 7)) << 3)];
#pragma unroll
        for (int mt = 0; mt < 2; ++mt)
          acc[mt][nt] = __builtin_amdgcn_mfma_f32_16x16x32_bf16(af[mt], bf, acc[mt][nt], 0, 0, 0);
      }
    }
    __builtin_amdgcn_sched_barrier(0);
    __builtin_amdgcn_s_barrier();
    __builtin_amdgcn_sched_barrier(0);
    if (it + 2 < 16) stage(buf, (it + 2) * 64);
  }

  // epilogue. C/D: row=q4*4+r, col=l16 (HW-validated convention)
  const int b = bt0 >> 11, t0 = bt0 & (T_ - 1);
  __bf16* ldsV = (__bf16*)&ldsB[0][0];
#pragma unroll
  for (int mt = 0; mt < 2; ++mt)
#pragma unroll
    for (int nt = 0; nt < 6; ++nt) {
      int gcol = cb0 + wn * 96 + nt * 16 + l16;
#pragma unroll
      for (int r = 0; r < 4; ++r) {
        int tl = wm * 32 + mt * 16 + q4 * 4 + r;
        float v = acc[mt][nt][r];
        if (gcol < 128) Qw[(size_t)(bt0 + tl) * H_ + gcol] = (__bf16)v;
        else if (gcol < 256) Kw[(size_t)(bt0 + tl) * H_ + (gcol - 128)] = (__bf16)v;
        else ldsV[(gcol - 256) * 72 + tl] = (__bf16)v;
      }
    }
  if (cb0 == 192) {
    __syncthreads();
#pragma unroll
    for (int i = 0; i < 4; ++i) {
      int idx = tid + 256 * i;
      int h = idx >> 3, t8 = (idx & 7) << 3;
      *(bf16x8*)(Vtw + ((size_t)b * H_ + h) * T_ + t0 + t8) =
          *(const bf16x8*)&ldsV[h * 72 + t8];
    }
  }
}

// ---------------- split-K causal flash attention, v3: counted-vmcnt pipeline --------
// grid (80, 8), block 256. Chunk = (qb, c). DMA-staged K/V (8 loads/thread/stage),
// double-buffered; per tile: vmcnt(8) -> barrier -> compute -> barrier -> stage(t+2).
__global__ __launch_bounds__(256) void attn_split(
    const __bf16* __restrict__ Q, const __bf16* __restrict__ K,
    const __bf16* __restrict__ Vt, __bf16* __restrict__ PO,
    float* __restrict__ Pl, float* __restrict__ out)
{
  __shared__ __align__(16) __bf16 ldsK[2][64 * 128];   // 2 x 16 KB
  __shared__ __align__(16) __bf16 ldsV[2][128 * 64];   // 2 x 16 KB
  __shared__ __align__(16) __bf16 ldsP[4][16 * 72];    // 9 KB (73 KB total -> 2 blk/CU)
  const int tid = threadIdx.x;
  const int wave = tid >> 6, lane = tid & 63;
  const int q4 = lane >> 4, l16 = lane & 15;
  const int b = blockIdx.y;
  int rem = blockIdx.x, qb = 0;
  while (rem >= (qb >> 3) + 1) { rem -= (qb >> 3) + 1; ++qb; }
  const int c = rem;
  const int tstart = c << 3;
  const int tend = min(tstart + 8, qb + 1);
  const int nch = (qb >> 3) + 1;
  const int qw = qb * 64 + wave * 16;
  const __bf16* Qb = Q + (size_t)b * T_ * H_;
  const __bf16* Kb = K + (size_t)b * T_ * H_;
  const __bf16* Vb = Vt + (size_t)b * H_ * T_;
  __bf16* ldsPw = &ldsP[wave][0];

  bf16x8 qf[4];
#pragma unroll
  for (int kc = 0; kc < 4; ++kc)
    qf[kc] = *(const bf16x8*)(Qb + (size_t)(qw + l16) * H_ + kc * 32 + q4 * 8);

  const f32x4 zero4 = {0.f, 0.f, 0.f, 0.f};
  f32x4 o[8];
#pragma unroll
  for (int nt = 0; nt < 8; ++nt) o[nt] = zero4;
  float lsum[4] = {0.f, 0.f, 0.f, 0.f};

  auto stageKV = [&](int bufi, int t) {
    const int kv0 = t << 6;
#pragma unroll
    for (int i = 0; i < 4; ++i) {
      int kr = i * 16 + (tid >> 4);
      gload16((char*)&ldsK[bufi][0] + i * 4096 + wave * 1024,
              Kb + (size_t)(kv0 + kr) * H_ + (((tid & 15) ^ (kr & 7)) << 3));
      int vr = i * 32 + (tid >> 3);
      gload16((char*)&ldsV[bufi][0] + i * 4096 + wave * 1024,
              Vb + (size_t)vr * T_ + kv0 + (((tid & 7) ^ (vr & 7)) << 3));
    }
  };

  stageKV(0, tstart);
  if (tstart + 1 < tend) stageKV(1, tstart + 1);

  for (int t = tstart; t < tend; ++t) {
    const int buf = (t - tstart) & 1;
    const int kv0 = t << 6;
    if (t + 1 < tend) asm volatile("s_waitcnt vmcnt(8)" ::: "memory");
    else              asm volatile("s_waitcnt vmcnt(0)" ::: "memory");
    __builtin_amdgcn_sched_barrier(0);
    __builtin_amdgcn_s_barrier();
    __builtin_amdgcn_sched_barrier(0);

    f32x4 s[4];
#pragma unroll
    for (int nt = 0; nt < 4; ++nt) s[nt] = zero4;
#pragma unroll
    for (int nt = 0; nt < 4; ++nt) {
      const int krow = nt * 16 + l16;
      const int kx = krow & 7;
#pragma unroll
      for (int kc = 0; kc < 4; ++kc) {
        bf16x8 kf = *(const bf16x8*)&ldsK[buf][krow * 128 + (((kc * 4 + q4) ^ kx) << 3)];
        s[nt] = __builtin_amdgcn_mfma_f32_16x16x32_bf16(qf[kc], kf, s[nt], 0, 0, 0);
      }
    }

    if (t == qb) {
#pragma unroll
      for (int r = 0; r < 4; ++r) {
        const int grow = qw + q4 * 4 + r;
#pragma unroll
        for (int nt = 0; nt < 4; ++nt) {
          int col = kv0 + nt * 16 + l16;
          float p = (col <= grow) ? __expf(s[nt][r] * 0.08838834764831845f) : 0.f;
          lsum[r] += p;
          ldsPw[(q4 * 4 + r) * 72 + nt * 16 + l16] = (__bf16)p;
        }
      }
    } else {
#pragma unroll
      for (int r = 0; r < 4; ++r)
#pragma unroll
        for (int nt = 0; nt < 4; ++nt) {
          float p = __expf(s[nt][r] * 0.08838834764831845f);
          lsum[r] += p;
          ldsPw[(q4 * 4 + r) * 72 + nt * 16 + l16] = (__bf16)p;
        }
    }
#pragma unroll
    for (int kc2 = 0; kc2 < 2; ++kc2) {
      bf16x8 pf = *(const bf16x8*)&ldsPw[l16 * 72 + kc2 * 32 + q4 * 8];
#pragma unroll
      for (int nt = 0; nt < 8; ++nt) {
        const int vrow = nt * 16 + l16;
        bf16x8 vf = *(const bf16x8*)&ldsV[buf][vrow * 64 + (((kc2 * 4 + q4) ^ (vrow & 7)) << 3)];
        o[nt] = __builtin_amdgcn_mfma_f32_16x16x32_bf16(pf, vf, o[nt], 0, 0, 0);
      }
    }
    __builtin_amdgcn_sched_barrier(0);
    __builtin_amdgcn_s_barrier();
    __builtin_amdgcn_sched_barrier(0);
    if (t + 2 < tend) stageKV(buf, t + 2);
  }

  float lred[4];
#pragma unroll
  for (int r = 0; r < 4; ++r) {
    float l = lsum[r];
    l += __shfl_xor(l, 1);
    l += __shfl_xor(l, 2);
    l += __shfl_xor(l, 4);
    l += __shfl_xor(l, 8);
    lred[r] = l;
  }

  if (nch == 1) {
#pragma unroll
    for (int r = 0; r < 4; ++r) lred[r] = 1.f / lred[r];
#pragma unroll
    for (int nt = 0; nt < 8; ++nt)
#pragma unroll
      for (int r = 0; r < 4; ++r) {
        int row = qw + q4 * 4 + r;
        out[((size_t)b * T_ + row) * H_ + nt * 16 + l16] = o[nt][r] * lred[r];
      }
  } else {
    const int slot = b * 80 + qb + max(qb - 8, 0) + max(qb - 16, 0) + max(qb - 24, 0) + c;
    __bf16* POs = PO + (size_t)slot * 8192;
#pragma unroll
    for (int nt = 0; nt < 8; ++nt)
#pragma unroll
      for (int r = 0; r < 4; ++r)
        POs[(wave * 16 + q4 * 4 + r) * 128 + nt * 16 + l16] = (__bf16)o[nt][r];
    if (l16 == 0)
#pragma unroll
      for (int r = 0; r < 4; ++r)
        Pl[slot * 64 + wave * 16 + q4 * 4 + r] = lred[r];
  }
}

// ---------------- combine partials (qb >= 8), 16 rows/block ----------------
__global__ __launch_bounds__(256) void attn_combine(
    const __bf16* __restrict__ PO, const float* __restrict__ Pl,
    float* __restrict__ out)
{
  const int qb = 8 + (blockIdx.x >> 2);
  const int seg = blockIdx.x & 3;
  const int b = blockIdx.y;
  const int nch = (qb >> 3) + 1;
  const int slot0 = b * 80 + qb + max(qb - 8, 0) + max(qb - 16, 0) + max(qb - 24, 0);
  const int tid = threadIdx.x;
  const int rloc = seg * 16 + (tid >> 4);   // row within qb block
  const int col8 = (tid & 15) << 3;
  float oacc[8] = {0.f};
  float lacc = 0.f;
  for (int cc = 0; cc < nch; ++cc) {
    const int slot = slot0 + cc;
    lacc += Pl[slot * 64 + rloc];
    bf16x8 v = *(const bf16x8*)(PO + (size_t)slot * 8192 + rloc * 128 + col8);
#pragma unroll
    for (int j = 0; j < 8; ++j) oacc[j] += (float)v[j];
  }
  const float inv = 1.f / lacc;
  float* op = out + ((size_t)b * T_ + qb * 64 + rloc) * H_ + col8;
  fv4 v0, v1;
#pragma unroll
  for (int j = 0; j < 4; ++j) { v0[j] = oacc[j] * inv; v1[j] = oacc[4 + j] * inv; }
  *(fv4*)op = v0;
  *(fv4*)(op + 4) = v1;
}

// ---------------- fallback mono attention (round-7, HW-validated) ----------------
__global__ __launch_bounds__(256) void attn_mono(
    const __bf16* __restrict__ Q, const __bf16* __restrict__ K,
    const __bf16* __restrict__ Vt, float* __restrict__ out)
{
  __shared__ __align__(16) __bf16 ldsK[64 * 136];
  __shared__ __align__(16) __bf16 ldsV[128 * 72];
  __shared__ __align__(16) __bf16 ldsP[4][16 * 72];
  const int tid = threadIdx.x;
  const int wave = tid >> 6, lane = tid & 63;
  const int q4 = lane >> 4, l16 = lane & 15;
  const int qb = blockIdx.x, b = blockIdx.y;
  const int qw = qb * 64 + wave * 16;
  const __bf16* Qb = Q + (size_t)b * T_ * H_;
  const __bf16* Kb = K + (size_t)b * T_ * H_;
  const __bf16* Vb = Vt + (size_t)b * H_ * T_;
  __bf16* ldsPw = &ldsP[wave][0];

  bf16x8 qf[4];
#pragma unroll
  for (int kc = 0; kc < 4; ++kc)
    qf[kc] = *(const bf16x8*)(Qb + (size_t)(qw + l16) * H_ + kc * 32 + q4 * 8);

  const f32x4 zero4 = {0.f, 0.f, 0.f, 0.f};
  f32x4 o[8];
#pragma unroll
  for (int nt = 0; nt < 8; ++nt) o[nt] = zero4;
  float lsum[4] = {0.f, 0.f, 0.f, 0.f};
  const int ntile = qb + 1;

  bf16x8 kp[4], vp[4];
#pragma unroll
  for (int i = 0; i < 4; ++i) {
    int idx = tid + 256 * i;
    int krow = idx >> 4, kcol8 = (idx & 15) << 3;
    kp[i] = *(const bf16x8*)(Kb + (size_t)krow * H_ + kcol8);
    int vrow = idx >> 3, vcol8 = (idx & 7) << 3;
    vp[i] = *(const bf16x8*)(Vb + (size_t)vrow * T_ + vcol8);
  }

  for (int t = 0; t < ntile; ++t) {
    const int kv0 = t << 6;
#pragma unroll
    for (int i = 0; i < 4; ++i) {
      int idx = tid + 256 * i;
      int krow = idx >> 4, kcol8 = (idx & 15) << 3;
      *(bf16x8*)&ldsK[krow * 136 + kcol8] = kp[i];
      int vrow = idx >> 3, vcol8 = (idx & 7) << 3;
      *(bf16x8*)&ldsV[vrow * 72 + vcol8] = vp[i];
    }
    __syncthreads();
    int kvn = (t + 1 < ntile) ? (kv0 + 64) : kv0;
#pragma unroll
    for (int i = 0; i < 4; ++i) {
      int idx = tid + 256 * i;
      int krow = idx >> 4, kcol8 = (idx & 15) << 3;
      kp[i] = *(const bf16x8*)(Kb + (size_t)(kvn + krow) * H_ + kcol8);
      int vrow = idx >> 3, vcol8 = (idx & 7) << 3;
      vp[i] = *(const bf16x8*)(Vb + (size_t)vrow * T_ + kvn + vcol8);
    }
    f32x4 s[4];
#pragma unroll
    for (int nt = 0; nt < 4; ++nt) s[nt] = zero4;
#pragma unroll
    for (int nt = 0; nt < 4; ++nt)
#pragma unroll
      for (int kc = 0; kc < 4; ++kc) {
        bf16x8 kf = *(const bf16x8*)&ldsK[(nt * 16 + l16) * 136 + kc * 32 + q4 * 8];
        s[nt] = __builtin_amdgcn_mfma_f32_16x16x32_bf16(qf[kc], kf, s[nt], 0, 0, 0);
      }
#pragma unroll
    for (int r = 0; r < 4; ++r) {
      const int grow = qw + q4 * 4 + r;
#pragma unroll
      for (int nt = 0; nt < 4; ++nt) {
        int col = kv0 + nt * 16 + l16;
        float p = (col <= grow) ? __expf(s[nt][r] * 0.08838834764831845f) : 0.f;
        lsum[r] += p;
        ldsPw[(q4 * 4 + r) * 72 + nt * 16 + l16] = (__bf16)p;
      }
    }
#pragma unroll
    for (int kc2 = 0; kc2 < 2; ++kc2) {
      bf16x8 pf = *(const bf16x8*)&ldsPw[l16 * 72 + kc2 * 32 + q4 * 8];
#pragma unroll
      for (int nt = 0; nt < 8; ++nt) {
        bf16x8 vf = *(const bf16x8*)&ldsV[(nt * 16 + l16) * 72 + kc2 * 32 + q4 * 8];
        o[nt] = __builtin_amdgcn_mfma_f32_16x16x32_bf16(pf, vf, o[nt], 0, 0, 0);
      }
    }
    __syncthreads();
  }
  float rinv[4];
#pragma unroll
  for (int r = 0; r < 4; ++r) {
    float l = lsum[r];
    l += __shfl_xor(l, 1);
    l += __shfl_xor(l, 2);
    l += __shfl_xor(l, 4);
    l += __shfl_xor(l, 8);
    rinv[r] = 1.f / l;
  }
#pragma unroll
  for (int nt = 0; nt < 8; ++nt)
#pragma unroll
    for (int r = 0; r < 4; ++r) {
      int row = qw + q4 * 4 + r;
      out[((size_t)b * T_ + row) * H_ + nt * 16 + l16] = o[nt][r] * rinv[r];
    }
}

extern "C" void kernel_launch(void* const* d_in, const int* in_sizes, int n_in,
                              void* d_out, int out_size, void* d_ws, size_t ws_size,
                              hipStream_t stream) {
  const float* x  = (const float*)d_in[0];
  const float* Wq = (const float*)d_in[1];
  const float* Wk = (const float*)d_in[2];
  const float* Wv = (const float*)d_in[3];
  __bf16* ws = (__bf16*)d_ws;
  __bf16* Qw  = ws;                             // [B*T][H]   4 MB
  __bf16* Kw  = ws + (size_t)B_ * T_ * H_;      // [B*T][H]   4 MB
  __bf16* Vtw = ws + (size_t)2 * B_ * T_ * H_;  // [B][H][T]  4 MB
  __bf16* Wt  = ws + (size_t)3 * B_ * T_ * H_;  // [3][H][C]  0.75 MB
  const size_t bf16_elems = 6684672;            // 13,369,344 B
  __bf16* PO = ws + bf16_elems;                 // 640 x 8192 bf16 = 10.5 MB
  float* Pl = (float*)(ws + bf16_elems + (size_t)640 * 8192);  // 640 x 64 fp32
  const size_t need = bf16_elems * 2 + (size_t)640 * 8192 * 2 + (size_t)640 * 64 * 4;
  float* out = (float*)d_out;

  prep_kernel<<<dim3(8, 3), 256, 0, stream>>>(Wq, Wk, Wv, Wt);
  proj_kernel<<<dim3(256, 2), 256, 0, stream>>>(x, Wt, Qw, Kw, Vtw);
  if (ws_size >= need) {
    attn_split<<<dim3(80, 8), 256, 0, stream>>>(Qw, Kw, Vtw, PO, Pl, out);
    attn_combine<<<dim3(96, 8), 256, 0, stream>>>(PO, Pl, out);
  } else {
    attn_mono<<<dim3(32, 8), 256, 0, stream>>>(Qw, Kw, Vtw, out);
  }
}

// Round 5
// 152.433 us; speedup vs baseline: 1.7179x; 1.0345x over previous
//
#include <hip/hip_runtime.h>

typedef __bf16 bf16x8 __attribute__((ext_vector_type(8)));
typedef float f32x4 __attribute__((ext_vector_type(4)));
typedef float fv4 __attribute__((ext_vector_type(4)));

#define B_ 8
#define T_ 2048
#define C_ 1024
#define H_ 128

// async global->LDS, 16B per lane. LDS dest = wave-uniform base + lane*16.
__device__ __forceinline__ void gload16(void* lds, const void* g) {
  __builtin_amdgcn_global_load_lds(
      (const __attribute__((address_space(1))) void*)g,
      (__attribute__((address_space(3))) void*)lds, 16, 0, 0);
}

// ROUND-2 LESSON: no cross-block combine via device-scope fences (per-XCD L2
// non-coherence: attn_split 40 -> 160 us). Separate combine dispatch is cheap.
// ROUND-5: attn KVBLK=32 -> 37 KB LDS -> 4 blocks/CU (640-block grid fully
// co-resident, no dispatch tail) + batch-per-XCD pinning (b = flat%8) so each
// XCD's L2 holds exactly one batch's K/V (1 MB << 4 MB).

// ---------------- prep: W[1024][128] fp32 -> Wt[wsel][128][1024] bf16 ----------------
__global__ __launch_bounds__(256) void prep_kernel(
    const float* __restrict__ Wq, const float* __restrict__ Wk,
    const float* __restrict__ Wv, __bf16* __restrict__ Wt)
{
  __shared__ __bf16 ldsT[128 * 136];
  const int tid = threadIdx.x;
  const int k0 = blockIdx.x * 128;
  const int wsel = blockIdx.y;
  const float* W = wsel == 0 ? Wq : (wsel == 1 ? Wk : Wv);
#pragma unroll
  for (int i = 0; i < 16; ++i) {
    int fidx = tid + 256 * i;
    int k = fidx >> 5, h4 = (fidx & 31) << 2;
    fv4 w = *(const fv4*)(W + (size_t)(k0 + k) * H_ + h4);
#pragma unroll
    for (int j = 0; j < 4; ++j) ldsT[(h4 + j) * 136 + k] = (__bf16)w[j];
  }
  __syncthreads();
#pragma unroll
  for (int i = 0; i < 8; ++i) {
    int sidx = tid + 256 * i;
    int h = sidx >> 4, c8 = (sidx & 15) << 3;
    *(bf16x8*)(Wt + (size_t)wsel * H_ * C_ + (size_t)h * C_ + k0 + c8) =
        *(const bf16x8*)&ldsT[h * 136 + c8];
  }
}

// ---------------- fused QKV projection, v3 (round-4, unchanged) --------------------
__global__ __launch_bounds__(256) void proj_kernel(
    const float* __restrict__ x, const __bf16* __restrict__ Wt,
    __bf16* __restrict__ Qw, __bf16* __restrict__ Kw, __bf16* __restrict__ Vtw)
{
  __shared__ __align__(16) float ldsA[2][64 * 64];     // 2 x 16 KB
  __shared__ __align__(16) __bf16 ldsB[2][192 * 64];   // 2 x 24 KB  (total 80 KB)
  const int tid = threadIdx.x;
  const int wave = tid >> 6, lane = tid & 63;
  const int q4 = lane >> 4, l16 = lane & 15;
  const int wm = wave >> 1, wn = wave & 1;
  const int bt0 = blockIdx.x * 64;
  const int cb0 = blockIdx.y * 192;

  const int arow16 = tid >> 4, agx = tid & 15;
  const int bcol32 = tid >> 3, bgx = tid & 7;

  const f32x4 zero4 = {0.f, 0.f, 0.f, 0.f};
  f32x4 acc[2][6];
#pragma unroll
  for (int mt = 0; mt < 2; ++mt)
#pragma unroll
    for (int nt = 0; nt < 6; ++nt) acc[mt][nt] = zero4;

  auto stage = [&](int bufi, int k0) {
#pragma unroll
    for (int i = 0; i < 4; ++i) {
      int row = i * 16 + arow16;
      gload16((char*)&ldsA[bufi][0] + i * 4096 + wave * 1024,
              x + (size_t)(bt0 + row) * C_ + k0 + ((agx ^ (row & 7)) << 2));
    }
#pragma unroll
    for (int i = 0; i < 6; ++i) {
      int col = i * 32 + bcol32;
      gload16((char*)&ldsB[bufi][0] + i * 4096 + wave * 1024,
              Wt + (size_t)(cb0 + col) * C_ + k0 + ((bgx ^ (col & 7)) << 3));
    }
  };

  stage(0, 0);
  stage(1, 64);  // 20 loads in flight

  for (int it = 0; it < 16; ++it) {
    const int buf = it & 1;
    if (it < 15) asm volatile("s_waitcnt vmcnt(10)" ::: "memory");
    else         asm volatile("s_waitcnt vmcnt(0)" ::: "memory");
    __builtin_amdgcn_sched_barrier(0);
    __builtin_amdgcn_s_barrier();
    __builtin_amdgcn_sched_barrier(0);
#pragma unroll
    for (int kc = 0; kc < 2; ++kc) {
      bf16x8 af[2];
#pragma unroll
      for (int mt = 0; mt < 2; ++mt) {
        const int rl = wm * 32 + mt * 16 + l16;
        const int rx = rl & 7;
        fv4 a0 = *(const fv4*)&ldsA[buf][rl * 64 + (((kc * 8 + q4 * 2 + 0) ^ rx) << 2)];
        fv4 a1 = *(const fv4*)&ldsA[buf][rl * 64 + (((kc * 8 + q4 * 2 + 1) ^ rx) << 2)];
#pragma unroll
        for (int j = 0; j < 4; ++j) { af[mt][j] = (__bf16)a0[j]; af[mt][4 + j] = (__bf16)a1[j]; }
      }
#pragma unroll
      for (int nt = 0; nt < 6; ++nt) {
        const int cl = wn * 96 + nt * 16 + l16;
        bf16x8 bf = *(const bf16x8*)&ldsB[buf][cl * 64 + (((kc * 4 + q4) ^ (cl & 7)) << 3)];
#pragma unroll
        for (int mt = 0; mt < 2; ++mt)
          acc[mt][nt] = __builtin_amdgcn_mfma_f32_16x16x32_bf16(af[mt], bf, acc[mt][nt], 0, 0, 0);
      }
    }
    __builtin_amdgcn_sched_barrier(0);
    __builtin_amdgcn_s_barrier();
    __builtin_amdgcn_sched_barrier(0);
    if (it + 2 < 16) stage(buf, (it + 2) * 64);
  }

  // epilogue. C/D: row=q4*4+r, col=l16 (HW-validated convention)
  const int b = bt0 >> 11, t0 = bt0 & (T_ - 1);
  __bf16* ldsV = (__bf16*)&ldsB[0][0];
#pragma unroll
  for (int mt = 0; mt < 2; ++mt)
#pragma unroll
    for (int nt = 0; nt < 6; ++nt) {
      int gcol = cb0 + wn * 96 + nt * 16 + l16;
#pragma unroll
      for (int r = 0; r < 4; ++r) {
        int tl = wm * 32 + mt * 16 + q4 * 4 + r;
        float v = acc[mt][nt][r];
        if (gcol < 128) Qw[(size_t)(bt0 + tl) * H_ + gcol] = (__bf16)v;
        else if (gcol < 256) Kw[(size_t)(bt0 + tl) * H_ + (gcol - 128)] = (__bf16)v;
        else ldsV[(gcol - 256) * 72 + tl] = (__bf16)v;
      }
    }
  if (cb0 == 192) {
    __syncthreads();
#pragma unroll
    for (int i = 0; i < 4; ++i) {
      int idx = tid + 256 * i;
      int h = idx >> 3, t8 = (idx & 7) << 3;
      *(bf16x8*)(Vtw + ((size_t)b * H_ + h) * T_ + t0 + t8) =
          *(const bf16x8*)&ldsV[h * 72 + t8];
    }
  }
}

// ---------------- split-K causal flash attention, v4 ------------------------------
// Flat grid 640. b = flat%8 (batch-per-XCD pinning), chunk = flat/8 -> (qb, c).
// KVBLK=32 subtiles: LDS = 2x8(K) + 2x8(V) + 5(P) = 37 KB -> 4 blocks/CU, whole
// grid co-resident. DMA dbuf staging (4 gloads/thread/stage), counted vmcnt(4),
// one barrier pair per subtile. Rule-21 swizzles: K granule ^= (row&7);
// V granule ^= ((row>>1)&3)  (2-way per quarter-wave = free).
__global__ __launch_bounds__(256) void attn_split(
    const __bf16* __restrict__ Q, const __bf16* __restrict__ K,
    const __bf16* __restrict__ Vt, __bf16* __restrict__ PO,
    float* __restrict__ Pl, float* __restrict__ out)
{
  __shared__ __align__(16) __bf16 ldsK[2][32 * 128];   // 2 x 8 KB  [kv][h]
  __shared__ __align__(16) __bf16 ldsV[2][128 * 32];   // 2 x 8 KB  [h][kv]
  __shared__ __align__(16) __bf16 ldsP[4][16 * 40];    // 5 KB
  const int tid = threadIdx.x;
  const int wave = tid >> 6, lane = tid & 63;
  const int q4 = lane >> 4, l16 = lane & 15;
  const int flat = blockIdx.x;
  const int b = flat & 7;                 // linear-id % 8 == XCD (perf heuristic only)
  int rem = flat >> 3, qb = 0;
  while (rem >= (qb >> 3) + 1) { rem -= (qb >> 3) + 1; ++qb; }
  const int c = rem;
  const int tstart = c << 3;
  const int tend = min(tstart + 8, qb + 1);
  const int nst = 2 * (tend - tstart);    // 32-row subtiles
  const int nch = (qb >> 3) + 1;
  const int qw = qb * 64 + wave * 16;
  const __bf16* Qb = Q + (size_t)b * T_ * H_;
  const __bf16* Kb = K + (size_t)b * T_ * H_;
  const __bf16* Vb = Vt + (size_t)b * H_ * T_;
  __bf16* ldsPw = &ldsP[wave][0];

  bf16x8 qf[4];
#pragma unroll
  for (int kc = 0; kc < 4; ++kc)
    qf[kc] = *(const bf16x8*)(Qb + (size_t)(qw + l16) * H_ + kc * 32 + q4 * 8);

  const f32x4 zero4 = {0.f, 0.f, 0.f, 0.f};
  f32x4 o[8];
#pragma unroll
  for (int nt = 0; nt < 8; ++nt) o[nt] = zero4;
  float lsum[4] = {0.f, 0.f, 0.f, 0.f};

  // stage one 32-row K/V subtile: 4 gload16 per thread
  auto stageKV = [&](int bufi, int kv0) {
#pragma unroll
    for (int i = 0; i < 2; ++i) {
      int idx = tid + 256 * i;
      int kr = idx >> 4, kg = idx & 15;
      gload16((char*)&ldsK[bufi][0] + i * 4096 + wave * 1024,
              Kb + (size_t)(kv0 + kr) * H_ + ((kg ^ (kr & 7)) << 3));
      int vr = idx >> 2, vg = idx & 3;
      gload16((char*)&ldsV[bufi][0] + i * 4096 + wave * 1024,
              Vb + (size_t)vr * T_ + kv0 + ((vg ^ ((vr >> 1) & 3)) << 3));
    }
  };

  const int kvbase = tstart << 6;
  stageKV(0, kvbase);
  stageKV(1, kvbase + 32);

  for (int ht = 0; ht < nst; ++ht) {
    const int buf = ht & 1;
    const int kv0 = kvbase + ht * 32;
    if (ht + 1 < nst) asm volatile("s_waitcnt vmcnt(4)" ::: "memory");
    else              asm volatile("s_waitcnt vmcnt(0)" ::: "memory");
    __builtin_amdgcn_sched_barrier(0);
    __builtin_amdgcn_s_barrier();
    __builtin_amdgcn_sched_barrier(0);

    f32x4 s[2];
    s[0] = zero4; s[1] = zero4;
#pragma unroll
    for (int nt2 = 0; nt2 < 2; ++nt2) {
      const int krow = nt2 * 16 + l16;
      const int kx = krow & 7;
#pragma unroll
      for (int kc = 0; kc < 4; ++kc) {
        bf16x8 kf = *(const bf16x8*)&ldsK[buf][krow * 128 + (((kc * 4 + q4) ^ kx) << 3)];
        s[nt2] = __builtin_amdgcn_mfma_f32_16x16x32_bf16(qf[kc], kf, s[nt2], 0, 0, 0);
      }
    }

    if ((kv0 >> 6) == qb) {  // diagonal 64-block: elementwise causal mask
#pragma unroll
      for (int r = 0; r < 4; ++r) {
        const int grow = qw + q4 * 4 + r;
#pragma unroll
        for (int nt2 = 0; nt2 < 2; ++nt2) {
          int col = kv0 + nt2 * 16 + l16;
          float p = (col <= grow) ? __expf(s[nt2][r] * 0.08838834764831845f) : 0.f;
          lsum[r] += p;
          ldsPw[(q4 * 4 + r) * 40 + nt2 * 16 + l16] = (__bf16)p;
        }
      }
    } else {
#pragma unroll
      for (int r = 0; r < 4; ++r)
#pragma unroll
        for (int nt2 = 0; nt2 < 2; ++nt2) {
          float p = __expf(s[nt2][r] * 0.08838834764831845f);
          lsum[r] += p;
          ldsPw[(q4 * 4 + r) * 40 + nt2 * 16 + l16] = (__bf16)p;
        }
    }

    bf16x8 pf = *(const bf16x8*)&ldsPw[l16 * 40 + q4 * 8];
#pragma unroll
    for (int nt = 0; nt < 8; ++nt) {
      const int vrow = nt * 16 + l16;
      bf16x8 vf = *(const bf16x8*)&ldsV[buf][vrow * 32 + ((q4 ^ ((vrow >> 1) & 3)) << 3)];
      o[nt] = __builtin_amdgcn_mfma_f32_16x16x32_bf16(pf, vf, o[nt], 0, 0, 0);
    }
    __builtin_amdgcn_sched_barrier(0);
    __builtin_amdgcn_s_barrier();
    __builtin_amdgcn_sched_barrier(0);
    if (ht + 2 < nst) stageKV(buf, kv0 + 64);
  }

  float lred[4];
#pragma unroll
  for (int r = 0; r < 4; ++r) {
    float l = lsum[r];
    l += __shfl_xor(l, 1);
    l += __shfl_xor(l, 2);
    l += __shfl_xor(l, 4);
    l += __shfl_xor(l, 8);
    lred[r] = l;
  }

  if (nch == 1) {
#pragma unroll
    for (int r = 0; r < 4; ++r) lred[r] = 1.f / lred[r];
#pragma unroll
    for (int nt = 0; nt < 8; ++nt)
#pragma unroll
      for (int r = 0; r < 4; ++r) {
        int row = qw + q4 * 4 + r;
        out[((size_t)b * T_ + row) * H_ + nt * 16 + l16] = o[nt][r] * lred[r];
      }
  } else {
    const int slot = b * 80 + qb + max(qb - 8, 0) + max(qb - 16, 0) + max(qb - 24, 0) + c;
    __bf16* POs = PO + (size_t)slot * 8192;
#pragma unroll
    for (int nt = 0; nt < 8; ++nt)
#pragma unroll
      for (int r = 0; r < 4; ++r)
        POs[(wave * 16 + q4 * 4 + r) * 128 + nt * 16 + l16] = (__bf16)o[nt][r];
    if (l16 == 0)
#pragma unroll
      for (int r = 0; r < 4; ++r)
        Pl[slot * 64 + wave * 16 + q4 * 4 + r] = lred[r];
  }
}

// ---------------- combine partials (qb >= 8), 16 rows/block ----------------
// Flat grid 768, batch-per-XCD pinning to match attn_split's PO locality.
__global__ __launch_bounds__(256) void attn_combine(
    const __bf16* __restrict__ PO, const float* __restrict__ Pl,
    float* __restrict__ out)
{
  const int flat = blockIdx.x;
  const int b = flat & 7;
  const int rest = flat >> 3;             // 0..95
  const int qb = 8 + (rest >> 2);
  const int seg = rest & 3;
  const int nch = (qb >> 3) + 1;
  const int slot0 = b * 80 + qb + max(qb - 8, 0) + max(qb - 16, 0) + max(qb - 24, 0);
  const int tid = threadIdx.x;
  const int rloc = seg * 16 + (tid >> 4);   // row within qb block
  const int col8 = (tid & 15) << 3;
  float oacc[8] = {0.f};
  float lacc = 0.f;
  for (int cc = 0; cc < nch; ++cc) {
    const int slot = slot0 + cc;
    lacc += Pl[slot * 64 + rloc];
    bf16x8 v = *(const bf16x8*)(PO + (size_t)slot * 8192 + rloc * 128 + col8);
#pragma unroll
    for (int j = 0; j < 8; ++j) oacc[j] += (float)v[j];
  }
  const float inv = 1.f / lacc;
  float* op = out + ((size_t)b * T_ + qb * 64 + rloc) * H_ + col8;
  fv4 v0, v1;
#pragma unroll
  for (int j = 0; j < 4; ++j) { v0[j] = oacc[j] * inv; v1[j] = oacc[4 + j] * inv; }
  *(fv4*)op = v0;
  *(fv4*)(op + 4) = v1;
}

// ---------------- fallback mono attention (round-7, HW-validated) ----------------
__global__ __launch_bounds__(256) void attn_mono(
    const __bf16* __restrict__ Q, const __bf16* __restrict__ K,
    const __bf16* __restrict__ Vt, float* __restrict__ out)
{
  __shared__ __align__(16) __bf16 ldsK[64 * 136];
  __shared__ __align__(16) __bf16 ldsV[128 * 72];
  __shared__ __align__(16) __bf16 ldsP[4][16 * 72];
  const int tid = threadIdx.x;
  const int wave = tid >> 6, lane = tid & 63;
  const int q4 = lane >> 4, l16 = lane & 15;
  const int qb = blockIdx.x, b = blockIdx.y;
  const int qw = qb * 64 + wave * 16;
  const __bf16* Qb = Q + (size_t)b * T_ * H_;
  const __bf16* Kb = K + (size_t)b * T_ * H_;
  const __bf16* Vb = Vt + (size_t)b * H_ * T_;
  __bf16* ldsPw = &ldsP[wave][0];

  bf16x8 qf[4];
#pragma unroll
  for (int kc = 0; kc < 4; ++kc)
    qf[kc] = *(const bf16x8*)(Qb + (size_t)(qw + l16) * H_ + kc * 32 + q4 * 8);

  const f32x4 zero4 = {0.f, 0.f, 0.f, 0.f};
  f32x4 o[8];
#pragma unroll
  for (int nt = 0; nt < 8; ++nt) o[nt] = zero4;
  float lsum[4] = {0.f, 0.f, 0.f, 0.f};
  const int ntile = qb + 1;

  bf16x8 kp[4], vp[4];
#pragma unroll
  for (int i = 0; i < 4; ++i) {
    int idx = tid + 256 * i;
    int krow = idx >> 4, kcol8 = (idx & 15) << 3;
    kp[i] = *(const bf16x8*)(Kb + (size_t)krow * H_ + kcol8);
    int vrow = idx >> 3, vcol8 = (idx & 7) << 3;
    vp[i] = *(const bf16x8*)(Vb + (size_t)vrow * T_ + vcol8);
  }

  for (int t = 0; t < ntile; ++t) {
    const int kv0 = t << 6;
#pragma unroll
    for (int i = 0; i < 4; ++i) {
      int idx = tid + 256 * i;
      int krow = idx >> 4, kcol8 = (idx & 15) << 3;
      *(bf16x8*)&ldsK[krow * 136 + kcol8] = kp[i];
      int vrow = idx >> 3, vcol8 = (idx & 7) << 3;
      *(bf16x8*)&ldsV[vrow * 72 + vcol8] = vp[i];
    }
    __syncthreads();
    int kvn = (t + 1 < ntile) ? (kv0 + 64) : kv0;
#pragma unroll
    for (int i = 0; i < 4; ++i) {
      int idx = tid + 256 * i;
      int krow = idx >> 4, kcol8 = (idx & 15) << 3;
      kp[i] = *(const bf16x8*)(Kb + (size_t)(kvn + krow) * H_ + kcol8);
      int vrow = idx >> 3, vcol8 = (idx & 7) << 3;
      vp[i] = *(const bf16x8*)(Vb + (size_t)vrow * T_ + kvn + vcol8);
    }
    f32x4 s[4];
#pragma unroll
    for (int nt = 0; nt < 4; ++nt) s[nt] = zero4;
#pragma unroll
    for (int nt = 0; nt < 4; ++nt)
#pragma unroll
      for (int kc = 0; kc < 4; ++kc) {
        bf16x8 kf = *(const bf16x8*)&ldsK[(nt * 16 + l16) * 136 + kc * 32 + q4 * 8];
        s[nt] = __builtin_amdgcn_mfma_f32_16x16x32_bf16(qf[kc], kf, s[nt], 0, 0, 0);
      }
#pragma unroll
    for (int r = 0; r < 4; ++r) {
      const int grow = qw + q4 * 4 + r;
#pragma unroll
      for (int nt = 0; nt < 4; ++nt) {
        int col = kv0 + nt * 16 + l16;
        float p = (col <= grow) ? __expf(s[nt][r] * 0.08838834764831845f) : 0.f;
        lsum[r] += p;
        ldsPw[(q4 * 4 + r) * 72 + nt * 16 + l16] = (__bf16)p;
      }
    }
#pragma unroll
    for (int kc2 = 0; kc2 < 2; ++kc2) {
      bf16x8 pf = *(const bf16x8*)&ldsPw[l16 * 72 + kc2 * 32 + q4 * 8];
#pragma unroll
      for (int nt = 0; nt < 8; ++nt) {
        bf16x8 vf = *(const bf16x8*)&ldsV[(nt * 16 + l16) * 72 + kc2 * 32 + q4 * 8];
        o[nt] = __builtin_amdgcn_mfma_f32_16x16x32_bf16(pf, vf, o[nt], 0, 0, 0);
      }
    }
    __syncthreads();
  }
  float rinv[4];
#pragma unroll
  for (int r = 0; r < 4; ++r) {
    float l = lsum[r];
    l += __shfl_xor(l, 1);
    l += __shfl_xor(l, 2);
    l += __shfl_xor(l, 4);
    l += __shfl_xor(l, 8);
    rinv[r] = 1.f / l;
  }
#pragma unroll
  for (int nt = 0; nt < 8; ++nt)
#pragma unroll
    for (int r = 0; r < 4; ++r) {
      int row = qw + q4 * 4 + r;
      out[((size_t)b * T_ + row) * H_ + nt * 16 + l16] = o[nt][r] * rinv[r];
    }
}

extern "C" void kernel_launch(void* const* d_in, const int* in_sizes, int n_in,
                              void* d_out, int out_size, void* d_ws, size_t ws_size,
                              hipStream_t stream) {
  const float* x  = (const float*)d_in[0];
  const float* Wq = (const float*)d_in[1];
  const float* Wk = (const float*)d_in[2];
  const float* Wv = (const float*)d_in[3];
  __bf16* ws = (__bf16*)d_ws;
  __bf16* Qw  = ws;                             // [B*T][H]   4 MB
  __bf16* Kw  = ws + (size_t)B_ * T_ * H_;      // [B*T][H]   4 MB
  __bf16* Vtw = ws + (size_t)2 * B_ * T_ * H_;  // [B][H][T]  4 MB
  __bf16* Wt  = ws + (size_t)3 * B_ * T_ * H_;  // [3][H][C]  0.75 MB
  const size_t bf16_elems = 6684672;            // 13,369,344 B
  __bf16* PO = ws + bf16_elems;                 // 640 x 8192 bf16 = 10.5 MB
  float* Pl = (float*)(ws + bf16_elems + (size_t)640 * 8192);  // 640 x 64 fp32
  const size_t need = bf16_elems * 2 + (size_t)640 * 8192 * 2 + (size_t)640 * 64 * 4;
  float* out = (float*)d_out;

  prep_kernel<<<dim3(8, 3), 256, 0, stream>>>(Wq, Wk, Wv, Wt);
  proj_kernel<<<dim3(256, 2), 256, 0, stream>>>(x, Wt, Qw, Kw, Vtw);
  if (ws_size >= need) {
    attn_split<<<640, 256, 0, stream>>>(Qw, Kw, Vtw, PO, Pl, out);
    attn_combine<<<768, 256, 0, stream>>>(PO, Pl, out);
  } else {
    attn_mono<<<dim3(32, 8), 256, 0, stream>>>(Qw, Kw, Vtw, out);
  }
}

// Round 6
// 149.224 us; speedup vs baseline: 1.7548x; 1.0215x over previous
//
#include <hip/hip_runtime.h>

typedef __bf16 bf16x8 __attribute__((ext_vector_type(8)));
typedef float f32x4 __attribute__((ext_vector_type(4)));
typedef float fv4 __attribute__((ext_vector_type(4)));

#define B_ 8
#define T_ 2048
#define C_ 1024
#define H_ 128

// async global->LDS, 16B per lane. LDS dest = wave-uniform base + lane*16.
__device__ __forceinline__ void gload16(void* lds, const void* g) {
  __builtin_amdgcn_global_load_lds(
      (const __attribute__((address_space(1))) void*)g,
      (__attribute__((address_space(3))) void*)lds, 16, 0, 0);
}

// ROUND-2 LESSON: no cross-block combine via device-scope fences (per-XCD L2
// non-coherence: attn_split 40 -> 160 us). Separate combine dispatch is cheap.
// ROUND-5 (kept): attn KVBLK=32 -> 4 blocks/CU, batch-per-XCD pinning.
// ROUND-6: proj 8-wave (512-thread) blocks: same 64x192 tile, same LDS/traffic,
// 16 waves/CU (4/SIMD) instead of 8 (2/SIMD) -> latency hiding for the barrier
// phases that counted-vmcnt alone couldn't cover (round-4 neutral).

// ---------------- prep: W[1024][128] fp32 -> Wt[wsel][128][1024] bf16 ----------------
__global__ __launch_bounds__(256) void prep_kernel(
    const float* __restrict__ Wq, const float* __restrict__ Wk,
    const float* __restrict__ Wv, __bf16* __restrict__ Wt)
{
  __shared__ __bf16 ldsT[128 * 136];
  const int tid = threadIdx.x;
  const int k0 = blockIdx.x * 128;
  const int wsel = blockIdx.y;
  const float* W = wsel == 0 ? Wq : (wsel == 1 ? Wk : Wv);
#pragma unroll
  for (int i = 0; i < 16; ++i) {
    int fidx = tid + 256 * i;
    int k = fidx >> 5, h4 = (fidx & 31) << 2;
    fv4 w = *(const fv4*)(W + (size_t)(k0 + k) * H_ + h4);
#pragma unroll
    for (int j = 0; j < 4; ++j) ldsT[(h4 + j) * 136 + k] = (__bf16)w[j];
  }
  __syncthreads();
#pragma unroll
  for (int i = 0; i < 8; ++i) {
    int sidx = tid + 256 * i;
    int h = sidx >> 4, c8 = (sidx & 15) << 3;
    *(bf16x8*)(Wt + (size_t)wsel * H_ * C_ + (size_t)h * C_ + k0 + c8) =
        *(const bf16x8*)&ldsT[h * 136 + c8];
  }
}

// ---------------- fused QKV projection, v4: 8-wave blocks --------------------------
// GEMM M=16384 N=384 K=1024. Block = 64 rows x 192 cols, 512 threads (8 waves, 2x4),
// wave tile 32x48 = acc[2][3]. grid (256,2) -> 2 blocks/CU, 16 waves/CU (4/SIMD).
// DMA staging 5 gloads/thread/stage (2 A + 3 B), counted vmcnt(5), rule-21 swizzle.
__global__ __launch_bounds__(512) void proj_kernel(
    const float* __restrict__ x, const __bf16* __restrict__ Wt,
    __bf16* __restrict__ Qw, __bf16* __restrict__ Kw, __bf16* __restrict__ Vtw)
{
  __shared__ __align__(16) float ldsA[2][64 * 64];     // 2 x 16 KB
  __shared__ __align__(16) __bf16 ldsB[2][192 * 64];   // 2 x 24 KB  (total 80 KB)
  const int tid = threadIdx.x;                          // 0..511
  const int wave = tid >> 6, lane = tid & 63;
  const int q4 = lane >> 4, l16 = lane & 15;
  const int wm = wave >> 2, wn = wave & 3;              // 2 m-halves x 4 n-quarters
  const int bt0 = blockIdx.x * 64;
  const int cb0 = blockIdx.y * 192;

  const int arow = tid >> 4, agx = tid & 15;   // A: 16B granules, 16 per 256B row
  const int bcol = tid >> 3, bgx = tid & 7;    // B: 16B granules, 8 per 128B col

  const f32x4 zero4 = {0.f, 0.f, 0.f, 0.f};
  f32x4 acc[2][3];
#pragma unroll
  for (int mt = 0; mt < 2; ++mt)
#pragma unroll
    for (int nt = 0; nt < 3; ++nt) acc[mt][nt] = zero4;

  auto stage = [&](int bufi, int k0) {
#pragma unroll
    for (int i = 0; i < 2; ++i) {  // A: 2 x (512 thr x 16B) = 16 KB = 64 rows
      int row = i * 32 + arow;
      gload16((char*)&ldsA[bufi][0] + i * 8192 + wave * 1024,
              x + (size_t)(bt0 + row) * C_ + k0 + ((agx ^ (row & 7)) << 2));
    }
#pragma unroll
    for (int i = 0; i < 3; ++i) {  // B: 3 x 8 KB = 24 KB = 192 cols
      int col = i * 64 + bcol;
      gload16((char*)&ldsB[bufi][0] + i * 8192 + wave * 1024,
              Wt + (size_t)(cb0 + col) * C_ + k0 + ((bgx ^ (col & 7)) << 3));
    }
  };

  stage(0, 0);
  stage(1, 64);  // 10 loads in flight

  for (int it = 0; it < 16; ++it) {
    const int buf = it & 1;
    if (it < 15) asm volatile("s_waitcnt vmcnt(5)" ::: "memory");
    else         asm volatile("s_waitcnt vmcnt(0)" ::: "memory");
    __builtin_amdgcn_sched_barrier(0);
    __builtin_amdgcn_s_barrier();
    __builtin_amdgcn_sched_barrier(0);
#pragma unroll
    for (int kc = 0; kc < 2; ++kc) {
      bf16x8 af[2];
#pragma unroll
      for (int mt = 0; mt < 2; ++mt) {
        const int rl = wm * 32 + mt * 16 + l16;
        const int rx = rl & 7;
        fv4 a0 = *(const fv4*)&ldsA[buf][rl * 64 + (((kc * 8 + q4 * 2 + 0) ^ rx) << 2)];
        fv4 a1 = *(const fv4*)&ldsA[buf][rl * 64 + (((kc * 8 + q4 * 2 + 1) ^ rx) << 2)];
#pragma unroll
        for (int j = 0; j < 4; ++j) { af[mt][j] = (__bf16)a0[j]; af[mt][4 + j] = (__bf16)a1[j]; }
      }
#pragma unroll
      for (int nt = 0; nt < 3; ++nt) {
        const int cl = wn * 48 + nt * 16 + l16;
        bf16x8 bf = *(const bf16x8*)&ldsB[buf][cl * 64 + (((kc * 4 + q4) ^ (cl & 7)) << 3)];
#pragma unroll
        for (int mt = 0; mt < 2; ++mt)
          acc[mt][nt] = __builtin_amdgcn_mfma_f32_16x16x32_bf16(af[mt], bf, acc[mt][nt], 0, 0, 0);
      }
    }
    __builtin_amdgcn_sched_barrier(0);
    __builtin_amdgcn_s_barrier();
    __builtin_amdgcn_sched_barrier(0);
    if (it + 2 < 16) stage(buf, (it + 2) * 64);
  }

  // epilogue. C/D: row=q4*4+r, col=l16 (HW-validated convention)
  const int b = bt0 >> 11, t0 = bt0 & (T_ - 1);
  __bf16* ldsV = (__bf16*)&ldsB[0][0];  // 18 KB needed <= 24 KB, free after last barrier
#pragma unroll
  for (int mt = 0; mt < 2; ++mt)
#pragma unroll
    for (int nt = 0; nt < 3; ++nt) {
      int gcol = cb0 + wn * 48 + nt * 16 + l16;
#pragma unroll
      for (int r = 0; r < 4; ++r) {
        int tl = wm * 32 + mt * 16 + q4 * 4 + r;
        float v = acc[mt][nt][r];
        if (gcol < 128) Qw[(size_t)(bt0 + tl) * H_ + gcol] = (__bf16)v;
        else if (gcol < 256) Kw[(size_t)(bt0 + tl) * H_ + (gcol - 128)] = (__bf16)v;
        else ldsV[(gcol - 256) * 72 + tl] = (__bf16)v;
      }
    }
  if (cb0 == 192) {
    __syncthreads();
#pragma unroll
    for (int i = 0; i < 2; ++i) {
      int idx = tid + 512 * i;  // 128 h x 8 t-granules
      int h = idx >> 3, t8 = (idx & 7) << 3;
      *(bf16x8*)(Vtw + ((size_t)b * H_ + h) * T_ + t0 + t8) =
          *(const bf16x8*)&ldsV[h * 72 + t8];
    }
  }
}

// ---------------- split-K causal flash attention, v4 (round-5, unchanged) ----------
__global__ __launch_bounds__(256) void attn_split(
    const __bf16* __restrict__ Q, const __bf16* __restrict__ K,
    const __bf16* __restrict__ Vt, __bf16* __restrict__ PO,
    float* __restrict__ Pl, float* __restrict__ out)
{
  __shared__ __align__(16) __bf16 ldsK[2][32 * 128];   // 2 x 8 KB  [kv][h]
  __shared__ __align__(16) __bf16 ldsV[2][128 * 32];   // 2 x 8 KB  [h][kv]
  __shared__ __align__(16) __bf16 ldsP[4][16 * 40];    // 5 KB
  const int tid = threadIdx.x;
  const int wave = tid >> 6, lane = tid & 63;
  const int q4 = lane >> 4, l16 = lane & 15;
  const int flat = blockIdx.x;
  const int b = flat & 7;                 // linear-id % 8 == XCD (perf heuristic only)
  int rem = flat >> 3, qb = 0;
  while (rem >= (qb >> 3) + 1) { rem -= (qb >> 3) + 1; ++qb; }
  const int c = rem;
  const int tstart = c << 3;
  const int tend = min(tstart + 8, qb + 1);
  const int nst = 2 * (tend - tstart);    // 32-row subtiles
  const int nch = (qb >> 3) + 1;
  const int qw = qb * 64 + wave * 16;
  const __bf16* Qb = Q + (size_t)b * T_ * H_;
  const __bf16* Kb = K + (size_t)b * T_ * H_;
  const __bf16* Vb = Vt + (size_t)b * H_ * T_;
  __bf16* ldsPw = &ldsP[wave][0];

  bf16x8 qf[4];
#pragma unroll
  for (int kc = 0; kc < 4; ++kc)
    qf[kc] = *(const bf16x8*)(Qb + (size_t)(qw + l16) * H_ + kc * 32 + q4 * 8);

  const f32x4 zero4 = {0.f, 0.f, 0.f, 0.f};
  f32x4 o[8];
#pragma unroll
  for (int nt = 0; nt < 8; ++nt) o[nt] = zero4;
  float lsum[4] = {0.f, 0.f, 0.f, 0.f};

  auto stageKV = [&](int bufi, int kv0) {
#pragma unroll
    for (int i = 0; i < 2; ++i) {
      int idx = tid + 256 * i;
      int kr = idx >> 4, kg = idx & 15;
      gload16((char*)&ldsK[bufi][0] + i * 4096 + wave * 1024,
              Kb + (size_t)(kv0 + kr) * H_ + ((kg ^ (kr & 7)) << 3));
      int vr = idx >> 2, vg = idx & 3;
      gload16((char*)&ldsV[bufi][0] + i * 4096 + wave * 1024,
              Vb + (size_t)vr * T_ + kv0 + ((vg ^ ((vr >> 1) & 3)) << 3));
    }
  };

  const int kvbase = tstart << 6;
  stageKV(0, kvbase);
  stageKV(1, kvbase + 32);

  for (int ht = 0; ht < nst; ++ht) {
    const int buf = ht & 1;
    const int kv0 = kvbase + ht * 32;
    if (ht + 1 < nst) asm volatile("s_waitcnt vmcnt(4)" ::: "memory");
    else              asm volatile("s_waitcnt vmcnt(0)" ::: "memory");
    __builtin_amdgcn_sched_barrier(0);
    __builtin_amdgcn_s_barrier();
    __builtin_amdgcn_sched_barrier(0);

    f32x4 s[2];
    s[0] = zero4; s[1] = zero4;
#pragma unroll
    for (int nt2 = 0; nt2 < 2; ++nt2) {
      const int krow = nt2 * 16 + l16;
      const int kx = krow & 7;
#pragma unroll
      for (int kc = 0; kc < 4; ++kc) {
        bf16x8 kf = *(const bf16x8*)&ldsK[buf][krow * 128 + (((kc * 4 + q4) ^ kx) << 3)];
        s[nt2] = __builtin_amdgcn_mfma_f32_16x16x32_bf16(qf[kc], kf, s[nt2], 0, 0, 0);
      }
    }

    if ((kv0 >> 6) == qb) {  // diagonal 64-block: elementwise causal mask
#pragma unroll
      for (int r = 0; r < 4; ++r) {
        const int grow = qw + q4 * 4 + r;
#pragma unroll
        for (int nt2 = 0; nt2 < 2; ++nt2) {
          int col = kv0 + nt2 * 16 + l16;
          float p = (col <= grow) ? __expf(s[nt2][r] * 0.08838834764831845f) : 0.f;
          lsum[r] += p;
          ldsPw[(q4 * 4 + r) * 40 + nt2 * 16 + l16] = (__bf16)p;
        }
      }
    } else {
#pragma unroll
      for (int r = 0; r < 4; ++r)
#pragma unroll
        for (int nt2 = 0; nt2 < 2; ++nt2) {
          float p = __expf(s[nt2][r] * 0.08838834764831845f);
          lsum[r] += p;
          ldsPw[(q4 * 4 + r) * 40 + nt2 * 16 + l16] = (__bf16)p;
        }
    }

    bf16x8 pf = *(const bf16x8*)&ldsPw[l16 * 40 + q4 * 8];
#pragma unroll
    for (int nt = 0; nt < 8; ++nt) {
      const int vrow = nt * 16 + l16;
      bf16x8 vf = *(const bf16x8*)&ldsV[buf][vrow * 32 + ((q4 ^ ((vrow >> 1) & 3)) << 3)];
      o[nt] = __builtin_amdgcn_mfma_f32_16x16x32_bf16(pf, vf, o[nt], 0, 0, 0);
    }
    __builtin_amdgcn_sched_barrier(0);
    __builtin_amdgcn_s_barrier();
    __builtin_amdgcn_sched_barrier(0);
    if (ht + 2 < nst) stageKV(buf, kv0 + 64);
  }

  float lred[4];
#pragma unroll
  for (int r = 0; r < 4; ++r) {
    float l = lsum[r];
    l += __shfl_xor(l, 1);
    l += __shfl_xor(l, 2);
    l += __shfl_xor(l, 4);
    l += __shfl_xor(l, 8);
    lred[r] = l;
  }

  if (nch == 1) {
#pragma unroll
    for (int r = 0; r < 4; ++r) lred[r] = 1.f / lred[r];
#pragma unroll
    for (int nt = 0; nt < 8; ++nt)
#pragma unroll
      for (int r = 0; r < 4; ++r) {
        int row = qw + q4 * 4 + r;
        out[((size_t)b * T_ + row) * H_ + nt * 16 + l16] = o[nt][r] * lred[r];
      }
  } else {
    const int slot = b * 80 + qb + max(qb - 8, 0) + max(qb - 16, 0) + max(qb - 24, 0) + c;
    __bf16* POs = PO + (size_t)slot * 8192;
#pragma unroll
    for (int nt = 0; nt < 8; ++nt)
#pragma unroll
      for (int r = 0; r < 4; ++r)
        POs[(wave * 16 + q4 * 4 + r) * 128 + nt * 16 + l16] = (__bf16)o[nt][r];
    if (l16 == 0)
#pragma unroll
      for (int r = 0; r < 4; ++r)
        Pl[slot * 64 + wave * 16 + q4 * 4 + r] = lred[r];
  }
}

// ---------------- combine partials (qb >= 8), 16 rows/block ----------------
__global__ __launch_bounds__(256) void attn_combine(
    const __bf16* __restrict__ PO, const float* __restrict__ Pl,
    float* __restrict__ out)
{
  const int flat = blockIdx.x;
  const int b = flat & 7;
  const int rest = flat >> 3;             // 0..95
  const int qb = 8 + (rest >> 2);
  const int seg = rest & 3;
  const int nch = (qb >> 3) + 1;
  const int slot0 = b * 80 + qb + max(qb - 8, 0) + max(qb - 16, 0) + max(qb - 24, 0);
  const int tid = threadIdx.x;
  const int rloc = seg * 16 + (tid >> 4);   // row within qb block
  const int col8 = (tid & 15) << 3;
  float oacc[8] = {0.f};
  float lacc = 0.f;
  for (int cc = 0; cc < nch; ++cc) {
    const int slot = slot0 + cc;
    lacc += Pl[slot * 64 + rloc];
    bf16x8 v = *(const bf16x8*)(PO + (size_t)slot * 8192 + rloc * 128 + col8);
#pragma unroll
    for (int j = 0; j < 8; ++j) oacc[j] += (float)v[j];
  }
  const float inv = 1.f / lacc;
  float* op = out + ((size_t)b * T_ + qb * 64 + rloc) * H_ + col8;
  fv4 v0, v1;
#pragma unroll
  for (int j = 0; j < 4; ++j) { v0[j] = oacc[j] * inv; v1[j] = oacc[4 + j] * inv; }
  *(fv4*)op = v0;
  *(fv4*)(op + 4) = v1;
}

// ---------------- fallback mono attention (round-7, HW-validated) ----------------
__global__ __launch_bounds__(256) void attn_mono(
    const __bf16* __restrict__ Q, const __bf16* __restrict__ K,
    const __bf16* __restrict__ Vt, float* __restrict__ out)
{
  __shared__ __align__(16) __bf16 ldsK[64 * 136];
  __shared__ __align__(16) __bf16 ldsV[128 * 72];
  __shared__ __align__(16) __bf16 ldsP[4][16 * 72];
  const int tid = threadIdx.x;
  const int wave = tid >> 6, lane = tid & 63;
  const int q4 = lane >> 4, l16 = lane & 15;
  const int qb = blockIdx.x, b = blockIdx.y;
  const int qw = qb * 64 + wave * 16;
  const __bf16* Qb = Q + (size_t)b * T_ * H_;
  const __bf16* Kb = K + (size_t)b * T_ * H_;
  const __bf16* Vb = Vt + (size_t)b * H_ * T_;
  __bf16* ldsPw = &ldsP[wave][0];

  bf16x8 qf[4];
#pragma unroll
  for (int kc = 0; kc < 4; ++kc)
    qf[kc] = *(const bf16x8*)(Qb + (size_t)(qw + l16) * H_ + kc * 32 + q4 * 8);

  const f32x4 zero4 = {0.f, 0.f, 0.f, 0.f};
  f32x4 o[8];
#pragma unroll
  for (int nt = 0; nt < 8; ++nt) o[nt] = zero4;
  float lsum[4] = {0.f, 0.f, 0.f, 0.f};
  const int ntile = qb + 1;

  bf16x8 kp[4], vp[4];
#pragma unroll
  for (int i = 0; i < 4; ++i) {
    int idx = tid + 256 * i;
    int krow = idx >> 4, kcol8 = (idx & 15) << 3;
    kp[i] = *(const bf16x8*)(Kb + (size_t)krow * H_ + kcol8);
    int vrow = idx >> 3, vcol8 = (idx & 7) << 3;
    vp[i] = *(const bf16x8*)(Vb + (size_t)vrow * T_ + vcol8);
  }

  for (int t = 0; t < ntile; ++t) {
    const int kv0 = t << 6;
#pragma unroll
    for (int i = 0; i < 4; ++i) {
      int idx = tid + 256 * i;
      int krow = idx >> 4, kcol8 = (idx & 15) << 3;
      *(bf16x8*)&ldsK[krow * 136 + kcol8] = kp[i];
      int vrow = idx >> 3, vcol8 = (idx & 7) << 3;
      *(bf16x8*)&ldsV[vrow * 72 + vcol8] = vp[i];
    }
    __syncthreads();
    int kvn = (t + 1 < ntile) ? (kv0 + 64) : kv0;
#pragma unroll
    for (int i = 0; i < 4; ++i) {
      int idx = tid + 256 * i;
      int krow = idx >> 4, kcol8 = (idx & 15) << 3;
      kp[i] = *(const bf16x8*)(Kb + (size_t)(kvn + krow) * H_ + kcol8);
      int vrow = idx >> 3, vcol8 = (idx & 7) << 3;
      vp[i] = *(const bf16x8*)(Vb + (size_t)vrow * T_ + kvn + vcol8);
    }
    f32x4 s[4];
#pragma unroll
    for (int nt = 0; nt < 4; ++nt) s[nt] = zero4;
#pragma unroll
    for (int nt = 0; nt < 4; ++nt)
#pragma unroll
      for (int kc = 0; kc < 4; ++kc) {
        bf16x8 kf = *(const bf16x8*)&ldsK[(nt * 16 + l16) * 136 + kc * 32 + q4 * 8];
        s[nt] = __builtin_amdgcn_mfma_f32_16x16x32_bf16(qf[kc], kf, s[nt], 0, 0, 0);
      }
#pragma unroll
    for (int r = 0; r < 4; ++r) {
      const int grow = qw + q4 * 4 + r;
#pragma unroll
      for (int nt = 0; nt < 4; ++nt) {
        int col = kv0 + nt * 16 + l16;
        float p = (col <= grow) ? __expf(s[nt][r] * 0.08838834764831845f) : 0.f;
        lsum[r] += p;
        ldsPw[(q4 * 4 + r) * 72 + nt * 16 + l16] = (__bf16)p;
      }
    }
#pragma unroll
    for (int kc2 = 0; kc2 < 2; ++kc2) {
      bf16x8 pf = *(const bf16x8*)&ldsPw[l16 * 72 + kc2 * 32 + q4 * 8];
#pragma unroll
      for (int nt = 0; nt < 8; ++nt) {
        bf16x8 vf = *(const bf16x8*)&ldsV[(nt * 16 + l16) * 72 + kc2 * 32 + q4 * 8];
        o[nt] = __builtin_amdgcn_mfma_f32_16x16x32_bf16(pf, vf, o[nt], 0, 0, 0);
      }
    }
    __syncthreads();
  }
  float rinv[4];
#pragma unroll
  for (int r = 0; r < 4; ++r) {
    float l = lsum[r];
    l += __shfl_xor(l, 1);
    l += __shfl_xor(l, 2);
    l += __shfl_xor(l, 4);
    l += __shfl_xor(l, 8);
    rinv[r] = 1.f / l;
  }
#pragma unroll
  for (int nt = 0; nt < 8; ++nt)
#pragma unroll
    for (int r = 0; r < 4; ++r) {
      int row = qw + q4 * 4 + r;
      out[((size_t)b * T_ + row) * H_ + nt * 16 + l16] = o[nt][r] * rinv[r];
    }
}

extern "C" void kernel_launch(void* const* d_in, const int* in_sizes, int n_in,
                              void* d_out, int out_size, void* d_ws, size_t ws_size,
                              hipStream_t stream) {
  const float* x  = (const float*)d_in[0];
  const float* Wq = (const float*)d_in[1];
  const float* Wk = (const float*)d_in[2];
  const float* Wv = (const float*)d_in[3];
  __bf16* ws = (__bf16*)d_ws;
  __bf16* Qw  = ws;                             // [B*T][H]   4 MB
  __bf16* Kw  = ws + (size_t)B_ * T_ * H_;      // [B*T][H]   4 MB
  __bf16* Vtw = ws + (size_t)2 * B_ * T_ * H_;  // [B][H][T]  4 MB
  __bf16* Wt  = ws + (size_t)3 * B_ * T_ * H_;  // [3][H][C]  0.75 MB
  const size_t bf16_elems = 6684672;            // 13,369,344 B
  __bf16* PO = ws + bf16_elems;                 // 640 x 8192 bf16 = 10.5 MB
  float* Pl = (float*)(ws + bf16_elems + (size_t)640 * 8192);  // 640 x 64 fp32
  const size_t need = bf16_elems * 2 + (size_t)640 * 8192 * 2 + (size_t)640 * 64 * 4;
  float* out = (float*)d_out;

  prep_kernel<<<dim3(8, 3), 256, 0, stream>>>(Wq, Wk, Wv, Wt);
  proj_kernel<<<dim3(256, 2), 512, 0, stream>>>(x, Wt, Qw, Kw, Vtw);
  if (ws_size >= need) {
    attn_split<<<640, 256, 0, stream>>>(Qw, Kw, Vtw, PO, Pl, out);
    attn_combine<<<768, 256, 0, stream>>>(PO, Pl, out);
  } else {
    attn_mono<<<dim3(32, 8), 256, 0, stream>>>(Qw, Kw, Vtw, out);
  }
}